// Round 5
// baseline (927.436 us; speedup 1.0000x reference)
//
#include <hip/hip_runtime.h>
#include <hip/hip_bf16.h>

#define DEV static __device__ __forceinline__

typedef __attribute__((ext_vector_type(8))) short short8;
typedef __attribute__((ext_vector_type(4))) float f32x4;

// ---------- helpers ----------
DEV unsigned short f2b(float f){
  unsigned int u = __float_as_uint(f);
  return (unsigned short)((u + 0x7FFFu + ((u >> 16) & 1u)) >> 16);  // RNE
}
DEV float b2f(unsigned short h){ return __uint_as_float(((unsigned int)h) << 16); }
DEV float load_in(const void* p, size_t i, int isbf){
  return isbf ? b2f(((const unsigned short*)p)[i]) : ((const float*)p)[i];
}
DEV void load_lds16(const unsigned short* g, unsigned short* l){
  __builtin_amdgcn_global_load_lds(
      (const __attribute__((address_space(1))) void*)g,
      (__attribute__((address_space(3))) void*)l, 16, 0, 0);
}

// ---------- grid barrier (persistent megakernel) ----------
// Deadlock-safe by capacity: grid=256 blocks, LDS<=64KB, 256 threads ->
// worst case 1 block/CU x 256 CUs = all resident. Ordering: R3-proven
// release/acquire chain (syncthreads + threadfence -> ACQ_REL arrive on cnt;
// last arriver releases gen; waiters acquire gen). ACQUIRE spin (not relaxed)
// guarantees remote-update visibility; s_sleep throttles the L2-inv rate.
// Spin happens only while ALL blocks idle at the phase boundary, so the
// R3 hazard (inv racing concurrent streaming) is absent.
struct GBar { int gen; int cnt; };
#define NBLK 256

DEV void grid_sync(GBar* bar, int target){
  __syncthreads();
  if (threadIdx.x == 0){
    __threadfence();
    int prev = __hip_atomic_fetch_add(&bar->cnt, 1, __ATOMIC_ACQ_REL, __HIP_MEMORY_SCOPE_AGENT);
    if (prev == NBLK - 1){
      __hip_atomic_store(&bar->cnt, 0, __ATOMIC_RELAXED, __HIP_MEMORY_SCOPE_AGENT);
      __hip_atomic_store(&bar->gen, target, __ATOMIC_RELEASE, __HIP_MEMORY_SCOPE_AGENT);
    } else {
      while (__hip_atomic_load(&bar->gen, __ATOMIC_ACQUIRE, __HIP_MEMORY_SCOPE_AGENT) < target)
        __builtin_amdgcn_s_sleep(2);
    }
  }
  __syncthreads();
}

// ---------- dtype detect (smem scratch passed in) ----------
DEV int detect_isbf(const void* src, int* cnt){
  int tid = threadIdx.x;
  float v = b2f(((const unsigned short*)src)[2 * tid]);
  float av = fabsf(v);
  bool sane = ((av < 64.0f) && (av > 9.5e-7f)) || (v == 0.0f);
  unsigned long long m = __ballot(sane);
  if ((tid & 63) == 0) cnt[tid >> 6] = __popcll(m);
  __syncthreads();
  int tot = cnt[0] + cnt[1] + cnt[2] + cnt[3];
  __syncthreads();
  return tot > 128;
}

// ---------- params ----------
struct WDesc { const void* src; long src_off; unsigned short* dst; int K; int N; int tstart; };
struct SDesc { const void* src; int src_off; int dstart; };
struct MegaParams {
  WDesc w[12];
  SDesc s[22];
  int stotal;
  const void* src;
  float* sdst;            // smalls
  unsigned short* wt;
  float* xf; unsigned short* xb;
  unsigned short* qb;     // q|k|v contiguous (1M ushorts each)
  unsigned short* attb;
  float* pp;
  unsigned short* h1;
  float* states;
  GBar* bar;
  void* dout;
};

// ---------- ingest unit (one old ingest block) ----------
DEV void dev_ingest_unit(const MegaParams& P, int b, int isbf, char* smem){
  float (*tile)[33] = (float (*)[33])smem;   // 32x33 fp32 = 4224B
  int tid = threadIdx.x;
  if (b < 6144){
    int t = 0;
    #pragma unroll
    for (int i = 1; i < 12; ++i) if (b >= P.w[i].tstart) t = i;
    WDesc d = P.w[t];
    int r = b - d.tstart;
    int tiles_x = d.N >> 5;
    int tx = r % tiles_x, ty = r / tiles_x;
    int lx = tid & 31, ly = tid >> 5;   // 32 x 8
    #pragma unroll
    for (int i = 0; i < 4; ++i){
      int row = ty*32 + ly + i*8;
      int col = tx*32 + lx;
      tile[ly + i*8][lx] = load_in(d.src, (size_t)d.src_off + (size_t)row*d.N + col, isbf);
    }
    __syncthreads();
    #pragma unroll
    for (int i = 0; i < 4; ++i){
      int orow = tx*32 + ly + i*8;   // n
      int ocol = ty*32 + lx;         // k
      d.dst[(size_t)orow*d.K + ocol] = f2b(tile[lx][ly + i*8]);
    }
    __syncthreads();   // tile reuse guard (loop over units)
    return;
  }
  int mb = b - 6144;
  if (mb < 4096){
    int i = mb*256 + tid;
    float v = load_in(P.src, (size_t)i, isbf);
    P.xf[i] = v; P.xb[i] = f2b(v);
  } else {
    int i = (mb - 4096)*256 + tid;
    if (i < P.stotal){
      int t = 0;
      #pragma unroll
      for (int j = 1; j < 22; ++j) if (i >= P.s[j].dstart) t = j;
      P.sdst[i] = load_in(P.s[t].src, (size_t)P.s[t].src_off + (i - P.s[t].dstart), isbf);
    }
  }
}

// ---------- GEMM tile (dbuf prefetch + XOR swizzle, rounds 1-2) ----------
struct GemmArgs {
  const unsigned short* A;
  const unsigned short* Bt;
  const float* bias;
  float* Cf;
  unsigned short* Cb;
  int K;
  int lda, ldb, ldc;
  int cshift, cmask;
  size_t cstride;
  size_t cfz;
  int relu;
};

template<int BN>
DEV void dev_gemm(GemmArgs g, int bxi, int byi, int bzi, char* smem){
  constexpr int NI = (BN == 128) ? 4 : 2;
  constexpr int NJ = 4;
  constexpr int BPASS = BN / 32;
  unsigned short* sA = (unsigned short*)smem;            // 2 x 8192 ushorts (32KB)
  unsigned short* sB = (unsigned short*)(smem + 32768);  // 2 x BN*64 ushorts
  int tid = threadIdx.x;
  int koff = bzi * g.K;
  int K = g.K, lda = g.lda, ldb = g.ldb;
  size_t bm = (size_t)byi * 128, bn = (size_t)bxi * BN;
  int lane = tid & 63, wv = tid >> 6, quad = lane >> 4, l16 = lane & 15;
  int wm = (BN == 128) ? (wv >> 1) * 64 : wv * 32;
  int wn = (BN == 128) ? (wv & 1) * 64 : 0;
  f32x4 acc[NI][NJ];
  #pragma unroll
  for (int i=0;i<NI;++i)
    #pragma unroll
    for (int j=0;j<NJ;++j) acc[i][j] = (f32x4){0.f,0.f,0.f,0.f};
  int srow = tid >> 3;
  int schunk = (tid & 7) ^ (srow & 7);
  const unsigned short* Ap = g.A  + (bm + srow)*lda + koff + schunk*8;
  const unsigned short* Bp = g.Bt + (bn + srow)*ldb + koff + schunk*8;

  #define STAGE(buf, ko)                                                           \
    do {                                                                           \
      _Pragma("unroll")                                                            \
      for (int p = 0; p < 4; ++p)                                                  \
        load_lds16(Ap + (size_t)(p*32)*lda + (ko), sA + (buf)*8192 + p*2048 + tid*8); \
      _Pragma("unroll")                                                            \
      for (int p = 0; p < BPASS; ++p)                                              \
        load_lds16(Bp + (size_t)(p*32)*ldb + (ko), sB + (buf)*(BN*64) + p*2048 + tid*8); \
    } while (0)

  STAGE(0, 0);
  asm volatile("s_waitcnt vmcnt(0)" ::: "memory");
  __builtin_amdgcn_s_barrier();

  int nt = K >> 6;
  int cur = 0;
  for (int t = 0; t < nt; ++t){
    if (t + 1 < nt){
      STAGE(cur ^ 1, (t + 1) * 64);
      __builtin_amdgcn_sched_barrier(0);
    }
    #pragma unroll
    for (int kk = 0; kk < 2; ++kk){
      short8 af[NI], bfv[NJ];
      #pragma unroll
      for (int i=0;i<NI;++i){
        int row = wm + i*16 + l16;
        int ch  = (kk*4 + quad) ^ (row & 7);
        af[i] = *(const short8*)&sA[cur*8192 + row*64 + ch*8];
      }
      #pragma unroll
      for (int j=0;j<NJ;++j){
        int row = wn + j*16 + l16;
        int ch  = (kk*4 + quad) ^ (row & 7);
        bfv[j] = *(const short8*)&sB[cur*(BN*64) + row*64 + ch*8];
      }
      #pragma unroll
      for (int i=0;i<NI;++i)
        #pragma unroll
        for (int j=0;j<NJ;++j)
          acc[i][j] = __builtin_amdgcn_mfma_f32_16x16x32_bf16(af[i], bfv[j], acc[i][j], 0,0,0);
    }
    if (t + 1 < nt){
      asm volatile("s_waitcnt vmcnt(0)" ::: "memory");
      __builtin_amdgcn_s_barrier();
    }
    cur ^= 1;
  }
  #undef STAGE

  float* Cf = g.Cf ? g.Cf + (size_t)bzi * g.cfz : nullptr;
  unsigned short* Cb = g.Cb;
  #pragma unroll
  for (int j=0;j<NJ;++j){
    int col = (int)bn + wn + j*16 + l16;
    float bv = g.bias ? g.bias[col] : 0.f;
    size_t cbase = ((size_t)(col >> g.cshift))*g.cstride + (col & g.cmask);
    #pragma unroll
    for (int i=0;i<NI;++i){
      #pragma unroll
      for (int r=0;r<4;++r){
        int row = (int)bm + wm + i*16 + quad*4 + r;
        float v = acc[i][j][r] + bv;
        if (g.relu) v = fmaxf(v, 0.f);
        size_t idx = cbase + (size_t)row*g.ldc;
        if (Cf) Cf[idx] = v;
        if (Cb) Cb[idx] = f2b(v);
      }
    }
  }
}

// ---------- attention (two phases, identical math to round-4 kernels) ----------
#define ATT_S 1024
#define ATT_D 512

DEV void dev_attn_state(int c, int bh, const unsigned short* k, const unsigned short* v,
                        float* states, char* smem){
  unsigned short* sVt = (unsigned short*)smem;            // 64*72
  unsigned short* sKt = (unsigned short*)(smem + 9216);
  int tid = threadIdx.x;
  int b = bh >> 3, h = bh & 7;
  const size_t base = ((size_t)b*ATT_S + (size_t)c*64)*ATT_D + h*64;
  int lane = tid & 63, wv = tid >> 6, quad = lane >> 4, l16 = lane & 15;

  int t = lane, vc = wv*8;
  const unsigned short* vp = v + base + (size_t)t*ATT_D;
  const unsigned short* kp = k + base + (size_t)t*ATT_D;
  float4 v0 = *(const float4*)(vp + vc);
  float4 v1 = *(const float4*)(vp + vc + 32);
  float4 k0 = *(const float4*)(kp + vc);
  float4 k1 = *(const float4*)(kp + vc + 32);
  {
    const unsigned short* pv0 = (const unsigned short*)&v0;
    const unsigned short* pv1 = (const unsigned short*)&v1;
    const unsigned short* pk0 = (const unsigned short*)&k0;
    const unsigned short* pk1 = (const unsigned short*)&k1;
    #pragma unroll
    for (int e = 0; e < 8; ++e){
      sVt[(vc+e)*72 + t]    = pv0[e];
      sVt[(vc+32+e)*72 + t] = pv1[e];
      sKt[(vc+e)*72 + t]    = pk0[e];
      sKt[(vc+32+e)*72 + t] = pk1[e];
    }
  }
  __syncthreads();

  f32x4 acc[4];
  #pragma unroll
  for (int j=0;j<4;++j) acc[j] = (f32x4){0.f,0.f,0.f,0.f};
  #pragma unroll
  for (int kk=0;kk<2;++kk){
    short8 a = *(const short8*)&sVt[(wv*16 + l16)*72 + kk*32 + quad*8];
    #pragma unroll
    for (int j=0;j<4;++j){
      short8 bb = *(const short8*)&sKt[(j*16 + l16)*72 + kk*32 + quad*8];
      acc[j] = __builtin_amdgcn_mfma_f32_16x16x32_bf16(a, bb, acc[j], 0,0,0);
    }
  }
  float* st = states + ((size_t)bh*16 + c)*4096;
  #pragma unroll
  for (int j=0;j<4;++j)
    #pragma unroll
    for (int rr=0;rr<4;++rr)
      st[(wv*16 + quad*4 + rr)*64 + j*16 + l16] = acc[j][rr];
}

DEV void dev_attn_out(int c, int bh, const unsigned short* q, const unsigned short* k,
                      const unsigned short* v, const float* states,
                      unsigned short* att, char* smem){
  unsigned short* sQ  = (unsigned short*)smem;            // 64*72
  unsigned short* sK  = (unsigned short*)(smem + 9216);
  unsigned short* sVt = (unsigned short*)(smem + 18432);
  float*          sKV = (float*)(smem + 27648);           // 64*68 fp32
  int tid = threadIdx.x;
  int b = bh >> 3, h = bh & 7;
  const size_t base = ((size_t)b*ATT_S + (size_t)c*64)*ATT_D + h*64;
  int lane = tid & 63, wv = tid >> 6, quad = lane >> 4, l16 = lane & 15;

  // exclusive prefix sum of chunk states (fp32)
  float4 racc[4];
  #pragma unroll
  for (int u=0;u<4;++u) racc[u] = (float4){0.f,0.f,0.f,0.f};
  const float* sbase = states + (size_t)bh*16*4096;
  for (int cc = 0; cc < c; ++cc){
    const float4* sp = (const float4*)(sbase + (size_t)cc*4096);
    #pragma unroll
    for (int u=0;u<4;++u){
      float4 t4 = sp[tid + u*256];
      racc[u].x += t4.x; racc[u].y += t4.y; racc[u].z += t4.z; racc[u].w += t4.w;
    }
  }
  #pragma unroll
  for (int u=0;u<4;++u){
    int e = (tid + u*256)*4;
    int row = e >> 6, col = e & 63;
    *(float4*)&sKV[row*68 + col] = racc[u];
  }

  // stage Q, K row-major; V transposed
  int r = tid >> 2, c8 = (tid & 3)*8;
  const unsigned short* qp = q + base + (size_t)r*ATT_D;
  const unsigned short* kp = k + base + (size_t)r*ATT_D;
  float4 q0 = *(const float4*)(qp + c8);
  float4 q1 = *(const float4*)(qp + c8 + 32);
  float4 k0 = *(const float4*)(kp + c8);
  float4 k1 = *(const float4*)(kp + c8 + 32);
  int t = lane, vc = wv*8;
  const unsigned short* vp = v + base + (size_t)t*ATT_D;
  float4 v0 = *(const float4*)(vp + vc);
  float4 v1 = *(const float4*)(vp + vc + 32);
  *(float4*)&sQ[r*72 + c8]      = q0;
  *(float4*)&sQ[r*72 + c8 + 32] = q1;
  *(float4*)&sK[r*72 + c8]      = k0;
  *(float4*)&sK[r*72 + c8 + 32] = k1;
  {
    const unsigned short* pv0 = (const unsigned short*)&v0;
    const unsigned short* pv1 = (const unsigned short*)&v1;
    #pragma unroll
    for (int e=0;e<8;++e){
      sVt[(vc+e)*72 + t]    = pv0[e];
      sVt[(vc+32+e)*72 + t] = pv1[e];
    }
  }
  __syncthreads();

  // S = Q K^T
  f32x4 accS[4];
  #pragma unroll
  for (int j=0;j<4;++j) accS[j] = (f32x4){0.f,0.f,0.f,0.f};
  #pragma unroll
  for (int kk=0;kk<2;++kk){
    short8 a = *(const short8*)&sQ[(wv*16 + l16)*72 + kk*32 + quad*8];
    #pragma unroll
    for (int j=0;j<4;++j){
      short8 bb = *(const short8*)&sK[(j*16 + l16)*72 + kk*32 + quad*8];
      accS[j] = __builtin_amdgcn_mfma_f32_16x16x32_bf16(a, bb, accS[j], 0,0,0);
    }
  }
  __syncthreads();

  // masked S -> sK (bf16)
  #pragma unroll
  for (int j=0;j<4;++j)
    #pragma unroll
    for (int rr=0;rr<4;++rr){
      int i  = wv*16 + quad*4 + rr;
      int cj = j*16 + l16;
      sK[i*72 + cj] = f2b((i >= cj) ? accS[j][rr] : 0.f);
    }

  // att = Q @ KV_prefix
  f32x4 accO[4];
  #pragma unroll
  for (int j=0;j<4;++j) accO[j] = (f32x4){0.f,0.f,0.f,0.f};
  #pragma unroll
  for (int kk=0;kk<2;++kk){
    short8 a = *(const short8*)&sQ[(wv*16 + l16)*72 + kk*32 + quad*8];
    #pragma unroll
    for (int j=0;j<4;++j){
      const float* pf = &sKV[(j*16 + l16)*68 + kk*32 + quad*8];
      short8 bb;
      #pragma unroll
      for (int e=0;e<8;++e) ((unsigned short*)&bb)[e] = f2b(pf[e]);
      accO[j] = __builtin_amdgcn_mfma_f32_16x16x32_bf16(a, bb, accO[j], 0,0,0);
    }
  }
  __syncthreads();

  // att += S @ V
  #pragma unroll
  for (int kk=0;kk<2;++kk){
    short8 a = *(const short8*)&sK[(wv*16 + l16)*72 + kk*32 + quad*8];
    #pragma unroll
    for (int j=0;j<4;++j){
      short8 bb = *(const short8*)&sVt[(j*16 + l16)*72 + kk*32 + quad*8];
      accO[j] = __builtin_amdgcn_mfma_f32_16x16x32_bf16(a, bb, accO[j], 0,0,0);
    }
  }
  #pragma unroll
  for (int j=0;j<4;++j)
    #pragma unroll
    for (int rr=0;rr<4;++rr){
      int i  = wv*16 + quad*4 + rr;
      int cj = j*16 + l16;
      att[base + (size_t)i*ATT_D + cj] = f2b(accO[j][rr]);
    }
}

// ---------- residual add + LN (optional fused second LN -> outd) ----------
DEV void dev_add_ln(int u, const float* x, const float* p, int np, const float* bias,
                    const float* g, const float* bta,
                    float* outf, unsigned short* outb, void* outd, int isbf,
                    const float* g2, const float* b2){
  int row = u*4 + (threadIdx.x >> 6);
  int lane = threadIdx.x & 63;
  const float* xr = x + (size_t)row*512;
  float a[8];
  *(float4*)&a[0] = *(const float4*)(xr + lane*4);
  *(float4*)&a[4] = *(const float4*)(xr + 256 + lane*4);
  for (int s = 0; s < np; ++s){
    const float* pr = p + (size_t)s*1048576 + (size_t)row*512;
    float yb[8];
    *(float4*)&yb[0] = *(const float4*)(pr + lane*4);
    *(float4*)&yb[4] = *(const float4*)(pr + 256 + lane*4);
    #pragma unroll
    for (int e=0;e<8;++e) a[e] += yb[e];
  }
  if (bias){
    float bb2[8];
    *(float4*)&bb2[0] = *(const float4*)(bias + lane*4);
    *(float4*)&bb2[4] = *(const float4*)(bias + 256 + lane*4);
    #pragma unroll
    for (int e=0;e<8;++e) a[e] += bb2[e];
  }
  float s = 0.f, qq = 0.f;
  #pragma unroll
  for (int e=0;e<8;++e){ s += a[e]; qq += a[e]*a[e]; }
  #pragma unroll
  for (int off=32; off>0; off>>=1){
    s  += __shfl_xor(s,  off, 64);
    qq += __shfl_xor(qq, off, 64);
  }
  float mean = s * (1.f/512.f);
  float var  = qq * (1.f/512.f) - mean*mean;
  float rstd = rsqrtf(var + 1e-5f);
  float gg[8], bb[8];
  *(float4*)&gg[0] = *(const float4*)(g + lane*4);
  *(float4*)&gg[4] = *(const float4*)(g + 256 + lane*4);
  *(float4*)&bb[0] = *(const float4*)(bta + lane*4);
  *(float4*)&bb[4] = *(const float4*)(bta + 256 + lane*4);
  #pragma unroll
  for (int e=0;e<8;++e) a[e] = (a[e]-mean)*rstd*gg[e] + bb[e];
  if (g2){   // fused second LN (final encoder LN)
    float s2 = 0.f, q2 = 0.f;
    #pragma unroll
    for (int e=0;e<8;++e){ s2 += a[e]; q2 += a[e]*a[e]; }
    #pragma unroll
    for (int off=32; off>0; off>>=1){
      s2 += __shfl_xor(s2, off, 64);
      q2 += __shfl_xor(q2, off, 64);
    }
    float m2 = s2 * (1.f/512.f);
    float v2 = q2 * (1.f/512.f) - m2*m2;
    float r2 = rsqrtf(v2 + 1e-5f);
    float gg2[8], bb22[8];
    *(float4*)&gg2[0]  = *(const float4*)(g2 + lane*4);
    *(float4*)&gg2[4]  = *(const float4*)(g2 + 256 + lane*4);
    *(float4*)&bb22[0] = *(const float4*)(b2 + lane*4);
    *(float4*)&bb22[4] = *(const float4*)(b2 + 256 + lane*4);
    #pragma unroll
    for (int e=0;e<8;++e) a[e] = (a[e]-m2)*r2*gg2[e] + bb22[e];
  }
  if (outf){
    float* orow = outf + (size_t)row*512;
    *(float4*)(orow + lane*4)       = *(float4*)&a[0];
    *(float4*)(orow + 256 + lane*4) = *(float4*)&a[4];
  }
  if (outb){
    unsigned short* orow = outb + (size_t)row*512;
    #pragma unroll
    for (int e=0;e<4;++e){ orow[lane*4+e] = f2b(a[e]); orow[256+lane*4+e] = f2b(a[4+e]); }
  }
  if (outd){
    if (isbf){
      unsigned short* od = (unsigned short*)outd + (size_t)row*512;
      #pragma unroll
      for (int e=0;e<4;++e){ od[lane*4+e] = f2b(a[e]); od[256+lane*4+e] = f2b(a[4+e]); }
    } else {
      float* od = (float*)outd + (size_t)row*512;
      *(float4*)(od + lane*4)       = *(float4*)&a[0];
      *(float4*)(od + 256 + lane*4) = *(float4*)&a[4];
    }
  }
}

// ---------- the megakernel ----------
__global__ __launch_bounds__(256) void mega(MegaParams P){
  __shared__ __align__(16) char smem[65536];
  int bid = blockIdx.x;
  int sync_no = 0;
  int isbf = detect_isbf(P.src, (int*)smem);
  __syncthreads();

  // phase 0: ingest (weights transpose + src + smalls), grid-stride
  for (int u = bid; u < 10296; u += NBLK)
    dev_ingest_unit(P, u, isbf, smem);
  grid_sync(P.bar, ++sync_no);

  unsigned short* kb = P.qb + 1048576;
  unsigned short* vb = P.qb + 2097152;

  for (int l = 0; l < 2; ++l){
    unsigned short* WqkvT = P.wt + (size_t)l*3145728;   // [1536][512]
    unsigned short* WoT   = WqkvT + 786432;             // [512][512]
    unsigned short* W1T   = WqkvT + 1048576;            // [2048][512]
    unsigned short* W2T   = WqkvT + 2097152;            // [512][2048]
    float* base  = P.sdst + l*6656;
    float* p_bqkv= base;
    float* p_bo  = base + 1536;
    float* p_b1  = base + 2048;
    float* p_b2  = base + 4096;
    float* p_g1  = base + 4608;
    float* p_be1 = base + 5120;
    float* p_g2  = base + 5632;
    float* p_be2 = base + 6144;

    // QKV: BN=128, tiles 12x16 = 192
    {
      GemmArgs a = {P.xb, WqkvT, p_bqkv, nullptr, P.qb, 512, 512, 512, 512,
                    9, 511, 1048576, 0, 0};
      if (bid < 192) dev_gemm<128>(a, bid % 12, bid / 12, 0, smem);
    }
    grid_sync(P.bar, ++sync_no);

    dev_attn_state(bid & 15, bid >> 4, kb, vb, P.states, smem);
    grid_sync(P.bar, ++sync_no);

    dev_attn_out(bid & 15, bid >> 4, P.qb, kb, vb, P.states, P.attb, smem);
    grid_sync(P.bar, ++sync_no);

    // att @ Wo: BN=64, (8,16,2)
    {
      GemmArgs a = {P.attb, WoT, nullptr, P.pp, nullptr, 256, 512, 512, 512,
                    30, 0x3fffffff, 0, 1048576, 0};
      dev_gemm<64>(a, bid & 7, (bid >> 3) & 15, bid >> 7, smem);
    }
    grid_sync(P.bar, ++sync_no);

    dev_add_ln(bid,        P.xf, P.pp, 2, p_bo, p_g1, p_be1, P.xf, P.xb, nullptr, 0, nullptr, nullptr);
    dev_add_ln(bid + NBLK, P.xf, P.pp, 2, p_bo, p_g1, p_be1, P.xf, P.xb, nullptr, 0, nullptr, nullptr);
    grid_sync(P.bar, ++sync_no);

    // FFN up: BN=128, (16,16), bias+relu
    {
      GemmArgs a = {P.xb, W1T, p_b1, nullptr, P.h1, 512, 512, 512, 2048,
                    30, 0x3fffffff, 0, 0, 1};
      dev_gemm<128>(a, bid & 15, bid >> 4, 0, smem);
    }
    grid_sync(P.bar, ++sync_no);

    // FFN down: BN=64, (8,16,2), K=1024/split
    {
      GemmArgs a = {P.h1, W2T, nullptr, P.pp, nullptr, 1024, 2048, 2048, 512,
                    30, 0x3fffffff, 0, 1048576, 0};
      dev_gemm<64>(a, bid & 7, (bid >> 3) & 15, bid >> 7, smem);
    }
    grid_sync(P.bar, ++sync_no);

    if (l == 0){
      dev_add_ln(bid,        P.xf, P.pp, 2, p_b2, p_g2, p_be2, P.xf, P.xb, nullptr, 0, nullptr, nullptr);
      dev_add_ln(bid + NBLK, P.xf, P.pp, 2, p_b2, p_g2, p_be2, P.xf, P.xb, nullptr, 0, nullptr, nullptr);
      grid_sync(P.bar, ++sync_no);
    } else {
      // ln2 fused with final encoder LN -> d_out (dtype follows input)
      const float* p_gf  = P.sdst + 13312;
      const float* p_bef = P.sdst + 13824;
      dev_add_ln(bid,        P.xf, P.pp, 2, p_b2, p_g2, p_be2, nullptr, nullptr, P.dout, isbf, p_gf, p_bef);
      dev_add_ln(bid + NBLK, P.xf, P.pp, 2, p_b2, p_g2, p_be2, nullptr, nullptr, P.dout, isbf, p_gf, p_bef);
    }
  }
}

// ---------- host ----------
extern "C" void kernel_launch(void* const* d_in, const int* in_sizes, int n_in,
                              void* d_out, int out_size, void* d_ws, size_t ws_size,
                              hipStream_t stream)
{
  (void)in_sizes; (void)n_in; (void)out_size; (void)ws_size;
  const void* src = d_in[0];
  const void* Wq = d_in[1];  const void* bq = d_in[2];
  const void* Wk = d_in[3];  const void* bk = d_in[4];
  const void* Wv = d_in[5];  const void* bv = d_in[6];
  const void* Wo = d_in[7];  const void* bo = d_in[8];
  const void* W1 = d_in[9];  const void* b1 = d_in[10];
  const void* W2 = d_in[11]; const void* b2 = d_in[12];
  const void* g1 = d_in[13]; const void* be1 = d_in[14];
  const void* g2 = d_in[15]; const void* be2 = d_in[16];
  const void* gf = d_in[17]; const void* bef = d_in[18];

  char* W = (char*)d_ws;
  MegaParams P;
  P.src   = src;
  P.sdst  = (float*)(W + 256);
  P.wt    = (unsigned short*)(W + 65536);
  P.xf    = (float*)(W + 12648448);
  P.xb    = (unsigned short*)(W + 16842752);
  P.qb    = (unsigned short*)(W + 18939904);
  P.attb  = (unsigned short*)(W + 25231360);
  P.pp    = (float*)(W + 27328512);
  P.h1    = (unsigned short*)(W + 44105728);
  P.states= (float*)(W + 44105728);      // aliases h1 (disjoint lifetime)
  P.bar   = (GBar*)(W + 53477376);
  P.dout  = d_out;

  {
    const void* wsrc[6] = {Wq, Wk, Wv, Wo, W1, W2};
    int wK[6] = {512,512,512,512,512,2048};
    int wN[6] = {512,512,512,512,2048,512};
    long wsz[6] = {262144,262144,262144,262144,1048576,1048576};
    int tstart = 0; size_t dsto = 0;
    for (int l=0;l<2;++l)
      for (int ti=0;ti<6;++ti){
        int idx = l*6+ti;
        P.w[idx].src = wsrc[ti];
        P.w[idx].src_off = (long)l * wsz[ti];
        P.w[idx].dst = P.wt + dsto;
        P.w[idx].K = wK[ti]; P.w[idx].N = wN[ti];
        P.w[idx].tstart = tstart;
        tstart += (wK[ti]/32)*(wN[ti]/32);
        dsto += (size_t)wsz[ti];
      }
    const void* ss[10] = {bq,bk,bv,bo,b1,b2,g1,be1,g2,be2};
    int slen[10] = {512,512,512,512,2048,512,512,512,512,512};
    int dcur = 0, di = 0;
    for (int l=0;l<2;++l)
      for (int ti=0;ti<10;++ti){
        P.s[di].src = ss[ti];
        P.s[di].src_off = l * slen[ti];
        P.s[di].dstart = dcur;
        dcur += slen[ti]; ++di;
      }
    P.s[20].src = gf;  P.s[20].src_off = 0; P.s[20].dstart = dcur; dcur += 512;
    P.s[21].src = bef; P.s[21].src_off = 0; P.s[21].dstart = dcur; dcur += 512;
    P.stotal = dcur;   // 14336
  }

  hipMemsetAsync(P.bar, 0, sizeof(GBar), stream);
  mega<<<dim3(NBLK), 256, 0, stream>>>(P);
}

// Round 7
// 285.415 us; speedup vs baseline: 3.2494x; 3.2494x over previous
//
#include <hip/hip_runtime.h>
#include <hip/hip_bf16.h>

#define DEV static __device__ __forceinline__

typedef __attribute__((ext_vector_type(8))) short short8;
typedef __attribute__((ext_vector_type(4))) float f32x4;

// ---------- helpers ----------
DEV unsigned short f2b(float f){
  unsigned int u = __float_as_uint(f);
  return (unsigned short)((u + 0x7FFFu + ((u >> 16) & 1u)) >> 16);  // RNE
}
DEV float b2f(unsigned short h){ return __uint_as_float(((unsigned int)h) << 16); }
DEV float load_in(const void* p, size_t i, int isbf){
  return isbf ? b2f(((const unsigned short*)p)[i]) : ((const float*)p)[i];
}
DEV void load_lds16(const unsigned short* g, unsigned short* l){
  __builtin_amdgcn_global_load_lds(
      (const __attribute__((address_space(1))) void*)g,
      (__attribute__((address_space(3))) void*)l, 16, 0, 0);
}

// ---------- per-block dtype detection ----------
DEV int detect_isbf_block(const void* src){
  __shared__ int cnt[4];
  int tid = threadIdx.x;
  float v = b2f(((const unsigned short*)src)[2 * tid]);
  float av = fabsf(v);
  bool sane = ((av < 64.0f) && (av > 9.5e-7f)) || (v == 0.0f);
  unsigned long long m = __ballot(sane);
  if ((tid & 63) == 0) cnt[tid >> 6] = __popcll(m);
  __syncthreads();
  int tot = cnt[0] + cnt[1] + cnt[2] + cnt[3];
  __syncthreads();
  return tot > 128;
}

// ---------- combined ingest: weights transpose + src/smalls copy ----------
struct WDesc { const void* src; long src_off; unsigned short* dst; int K; int N; int tstart; };
struct SDesc { const void* src; int src_off; int dstart; };
struct IngestParams {
  WDesc w[12];
  SDesc s[22];
  float* sdst; int stotal;
  const void* src;
  float* xf; unsigned short* xb;
};

__global__ __launch_bounds__(256) void ingest_all(IngestParams P){
  __shared__ float tile[32][33];
  int b = blockIdx.x, tid = threadIdx.x;
  int isbf = detect_isbf_block(P.src);
  if (b < 6144){
    int t = 0;
    #pragma unroll
    for (int i = 1; i < 12; ++i) if (b >= P.w[i].tstart) t = i;
    WDesc d = P.w[t];
    int r = b - d.tstart;
    int tiles_x = d.N >> 5;
    int tx = r % tiles_x, ty = r / tiles_x;
    int lx = tid & 31, ly = tid >> 5;   // 32 x 8
    #pragma unroll
    for (int i = 0; i < 4; ++i){
      int row = ty*32 + ly + i*8;
      int col = tx*32 + lx;
      tile[ly + i*8][lx] = load_in(d.src, (size_t)d.src_off + (size_t)row*d.N + col, isbf);
    }
    __syncthreads();
    #pragma unroll
    for (int i = 0; i < 4; ++i){
      int orow = tx*32 + ly + i*8;   // n
      int ocol = ty*32 + lx;         // k
      d.dst[(size_t)orow*d.K + ocol] = f2b(tile[lx][ly + i*8]);
    }
    return;
  }
  int mb = b - 6144;
  if (mb < 4096){
    int i = mb*256 + tid;
    float v = load_in(P.src, (size_t)i, isbf);
    P.xf[i] = v; P.xb[i] = f2b(v);
  } else {
    int i = (mb - 4096)*256 + tid;
    if (i < P.stotal){
      int t = 0;
      #pragma unroll
      for (int j = 1; j < 22; ++j) if (i >= P.s[j].dstart) t = j;
      P.sdst[i] = load_in(P.s[t].src, (size_t)P.s[t].src_off + (i - P.s[t].dstart), isbf);
    }
  }
}

// ---------- GEMM: C[M][N] = A[M][K] @ Bt[N][K]^T (+bias) (A,Bt bf16) ----------
// Double-buffered prefetch (round 2), XOR-swizzled LDS (round 1).
struct GemmArgs {
  const unsigned short* A;
  const unsigned short* Bt;
  const float* bias;      // nullable
  float* Cf;              // nullable (fp32 partial base)
  unsigned short* Cb;     // nullable (bf16 out)
  int K;                  // per-split K
  int lda, ldb, ldc;
  int cshift, cmask;
  size_t cstride;         // col-split stride (elements)
  size_t cfz;             // Cf z-stride (elements)
  int relu;
};

template<int BN>
__global__ __launch_bounds__(256) void gemm_bt(GemmArgs g){
  constexpr int NI = (BN == 128) ? 4 : 2;
  constexpr int NJ = 4;
  constexpr int BPASS = BN / 32;          // 32-row staging passes for B
  __shared__ __align__(16) unsigned short sA[2][128*64];
  __shared__ __align__(16) unsigned short sB[2][BN*64];
  int tid = threadIdx.x;
  int koff = blockIdx.z * g.K;
  int K = g.K, lda = g.lda, ldb = g.ldb;
  size_t bm = (size_t)blockIdx.y * 128, bn = (size_t)blockIdx.x * BN;
  int lane = tid & 63, wv = tid >> 6, quad = lane >> 4, l16 = lane & 15;
  int wm = (BN == 128) ? (wv >> 1) * 64 : wv * 32;
  int wn = (BN == 128) ? (wv & 1) * 64 : 0;
  f32x4 acc[NI][NJ];
  #pragma unroll
  for (int i=0;i<NI;++i)
    #pragma unroll
    for (int j=0;j<NJ;++j) acc[i][j] = (f32x4){0.f,0.f,0.f,0.f};
  int srow = tid >> 3;                    // 0..31 within pass
  int schunk = (tid & 7) ^ (srow & 7);
  const unsigned short* Ap = g.A  + (bm + srow)*lda + koff + schunk*8;
  const unsigned short* Bp = g.Bt + (bn + srow)*ldb + koff + schunk*8;

  #define STAGE(buf, ko)                                                      \
    do {                                                                      \
      _Pragma("unroll")                                                       \
      for (int p = 0; p < 4; ++p)                                             \
        load_lds16(Ap + (size_t)(p*32)*lda + (ko), &sA[buf][p*2048 + tid*8]); \
      _Pragma("unroll")                                                       \
      for (int p = 0; p < BPASS; ++p)                                         \
        load_lds16(Bp + (size_t)(p*32)*ldb + (ko), &sB[buf][p*2048 + tid*8]); \
    } while (0)

  STAGE(0, 0);
  asm volatile("s_waitcnt vmcnt(0)" ::: "memory");
  __builtin_amdgcn_s_barrier();

  int nt = K >> 6;
  int cur = 0;
  for (int t = 0; t < nt; ++t){
    if (t + 1 < nt){
      STAGE(cur ^ 1, (t + 1) * 64);       // issue next-tile loads early
      __builtin_amdgcn_sched_barrier(0);  // keep issue before compute
    }
    #pragma unroll
    for (int kk = 0; kk < 2; ++kk){
      short8 af[NI], bfv[NJ];
      #pragma unroll
      for (int i=0;i<NI;++i){
        int row = wm + i*16 + l16;
        int ch  = (kk*4 + quad) ^ (row & 7);
        af[i] = *(const short8*)&sA[cur][row*64 + ch*8];
      }
      #pragma unroll
      for (int j=0;j<NJ;++j){
        int row = wn + j*16 + l16;
        int ch  = (kk*4 + quad) ^ (row & 7);
        bfv[j] = *(const short8*)&sB[cur][row*64 + ch*8];
      }
      #pragma unroll
      for (int i=0;i<NI;++i)
        #pragma unroll
        for (int j=0;j<NJ;++j)
          acc[i][j] = __builtin_amdgcn_mfma_f32_16x16x32_bf16(af[i], bfv[j], acc[i][j], 0,0,0);
    }
    if (t + 1 < nt){
      asm volatile("s_waitcnt vmcnt(0)" ::: "memory");
      __builtin_amdgcn_s_barrier();
    }
    cur ^= 1;
  }
  #undef STAGE

  float* Cf = g.Cf ? g.Cf + (size_t)blockIdx.z * g.cfz : nullptr;
  unsigned short* Cb = g.Cb;
  #pragma unroll
  for (int j=0;j<NJ;++j){
    int col = (int)bn + wn + j*16 + l16;
    float bv = g.bias ? g.bias[col] : 0.f;
    size_t cbase = ((size_t)(col >> g.cshift))*g.cstride + (col & g.cmask);
    #pragma unroll
    for (int i=0;i<NI;++i){
      #pragma unroll
      for (int r=0;r<4;++r){
        int row = (int)bm + wm + i*16 + quad*4 + r;
        float v = acc[i][j][r] + bv;
        if (g.relu) v = fmaxf(v, 0.f);
        size_t idx = cbase + (size_t)row*g.ldc;
        if (Cf) Cf[idx] = v;
        if (Cb) Cb[idx] = f2b(v);
      }
    }
  }
}

// ---------- fused chunked causal linear attention (one kernel, no sync) ----
// Block (c,bh) computes the prefix KV-state REDUNDANTLY: accumulates
// sum_{cc<c} V_cc^T K_cc by iterating previous chunks with MFMA (8/chunk).
// Traffic equivalence: old scheme read c x 16KB fp32 precomputed states; this
// reads c x 16KB bf16 K/V (L2-resident, K/V = 4MB total) -- same bytes, so
// the redundancy is ~free and one kernel + one boundary per layer disappears.
// No cross-block communication of any kind (R3/R5/R6 lesson).
#define ATT_S 1024
#define ATT_D 512

__global__ __launch_bounds__(256) void attn_kernel(
    const unsigned short* q, const unsigned short* k, const unsigned short* v,
    unsigned short* att)
{
  __shared__ __align__(16) unsigned short sQ  [64*72];
  __shared__ __align__(16) unsigned short sK  [64*72];   // K chunk, reused for S
  __shared__ __align__(16) unsigned short sVt [64*72];
  __shared__ __align__(16) unsigned short sKt2[64*72];   // prefix staging
  __shared__ __align__(16) unsigned short sVt2[64*72];
  __shared__ __align__(16) float sKV[64*68];
  int tid = threadIdx.x;
  int c = blockIdx.x, bh = blockIdx.y;
  int b = bh >> 3, h = bh & 7;
  const size_t base = ((size_t)b*ATT_S + (size_t)c*64)*ATT_D + h*64;
  int lane = tid & 63, wv = tid >> 6, quad = lane >> 4, l16 = lane & 15;

  // ---- stage own chunk: Q,K row-major; V transposed
  int r = tid >> 2, c8 = (tid & 3)*8;
  const unsigned short* qp = q + base + (size_t)r*ATT_D;
  const unsigned short* kp = k + base + (size_t)r*ATT_D;
  float4 q0 = *(const float4*)(qp + c8);
  float4 q1 = *(const float4*)(qp + c8 + 32);
  float4 k0 = *(const float4*)(kp + c8);
  float4 k1 = *(const float4*)(kp + c8 + 32);
  int t = lane, vc = wv*8;
  const unsigned short* vp = v + base + (size_t)t*ATT_D;
  float4 v0 = *(const float4*)(vp + vc);
  float4 v1 = *(const float4*)(vp + vc + 32);
  *(float4*)&sQ[r*72 + c8]      = q0;
  *(float4*)&sQ[r*72 + c8 + 32] = q1;
  *(float4*)&sK[r*72 + c8]      = k0;
  *(float4*)&sK[r*72 + c8 + 32] = k1;
  {
    const unsigned short* pv0 = (const unsigned short*)&v0;
    const unsigned short* pv1 = (const unsigned short*)&v1;
    #pragma unroll
    for (int e=0;e<8;++e){
      sVt[(vc+e)*72 + t]    = pv0[e];
      sVt[(vc+32+e)*72 + t] = pv1[e];
    }
  }
  __syncthreads();

  // ---- prefix state accumulate: accP += V_cc^T K_cc for cc < c
  f32x4 accP[4];
  #pragma unroll
  for (int j=0;j<4;++j) accP[j] = (f32x4){0.f,0.f,0.f,0.f};
  for (int cc = 0; cc < c; ++cc){
    const size_t pbase = ((size_t)b*ATT_S + (size_t)cc*64)*ATT_D + h*64;
    const unsigned short* pvp = v + pbase + (size_t)t*ATT_D;
    const unsigned short* pkp = k + pbase + (size_t)t*ATT_D;
    float4 pv0 = *(const float4*)(pvp + vc);
    float4 pv1 = *(const float4*)(pvp + vc + 32);
    float4 pk0 = *(const float4*)(pkp + vc);
    float4 pk1 = *(const float4*)(pkp + vc + 32);
    __syncthreads();   // prev iteration's MFMA reads of sVt2/sKt2 done
    {
      const unsigned short* a0 = (const unsigned short*)&pv0;
      const unsigned short* a1 = (const unsigned short*)&pv1;
      const unsigned short* b0 = (const unsigned short*)&pk0;
      const unsigned short* b1 = (const unsigned short*)&pk1;
      #pragma unroll
      for (int e=0;e<8;++e){
        sVt2[(vc+e)*72 + t]    = a0[e];
        sVt2[(vc+32+e)*72 + t] = a1[e];
        sKt2[(vc+e)*72 + t]    = b0[e];
        sKt2[(vc+32+e)*72 + t] = b1[e];
      }
    }
    __syncthreads();
    #pragma unroll
    for (int kk=0;kk<2;++kk){
      short8 a = *(const short8*)&sVt2[(wv*16 + l16)*72 + kk*32 + quad*8];
      #pragma unroll
      for (int j=0;j<4;++j){
        short8 bb = *(const short8*)&sKt2[(j*16 + l16)*72 + kk*32 + quad*8];
        accP[j] = __builtin_amdgcn_mfma_f32_16x16x32_bf16(a, bb, accP[j], 0,0,0);
      }
    }
  }
  // write prefix state (C/D layout: col=lane&15, row=(lane>>4)*4+reg) -> sKV
  #pragma unroll
  for (int j=0;j<4;++j)
    #pragma unroll
    for (int rr=0;rr<4;++rr)
      sKV[(wv*16 + quad*4 + rr)*68 + j*16 + l16] = accP[j][rr];

  // ---- S = Q K^T (sQ/sK staged & synced above)
  f32x4 accS[4];
  #pragma unroll
  for (int j=0;j<4;++j) accS[j] = (f32x4){0.f,0.f,0.f,0.f};
  #pragma unroll
  for (int kk=0;kk<2;++kk){
    short8 a = *(const short8*)&sQ[(wv*16 + l16)*72 + kk*32 + quad*8];
    #pragma unroll
    for (int j=0;j<4;++j){
      short8 bb = *(const short8*)&sK[(j*16 + l16)*72 + kk*32 + quad*8];
      accS[j] = __builtin_amdgcn_mfma_f32_16x16x32_bf16(a, bb, accS[j], 0,0,0);
    }
  }
  __syncthreads();   // sKV writes visible; all sK reads done before overwrite

  // masked S -> sK (bf16)
  #pragma unroll
  for (int j=0;j<4;++j)
    #pragma unroll
    for (int rr=0;rr<4;++rr){
      int i  = wv*16 + quad*4 + rr;
      int cj = j*16 + l16;
      sK[i*72 + cj] = f2b((i >= cj) ? accS[j][rr] : 0.f);
    }

  // att = Q @ KV_prefix (sKV converted bf16 on the fly)
  f32x4 accO[4];
  #pragma unroll
  for (int j=0;j<4;++j) accO[j] = (f32x4){0.f,0.f,0.f,0.f};
  #pragma unroll
  for (int kk=0;kk<2;++kk){
    short8 a = *(const short8*)&sQ[(wv*16 + l16)*72 + kk*32 + quad*8];
    #pragma unroll
    for (int j=0;j<4;++j){
      const float* pf = &sKV[(j*16 + l16)*68 + kk*32 + quad*8];
      short8 bb;
      #pragma unroll
      for (int e=0;e<8;++e) ((unsigned short*)&bb)[e] = f2b(pf[e]);
      accO[j] = __builtin_amdgcn_mfma_f32_16x16x32_bf16(a, bb, accO[j], 0,0,0);
    }
  }
  __syncthreads();   // masked S visible to all waves

  // att += S @ V
  #pragma unroll
  for (int kk=0;kk<2;++kk){
    short8 a = *(const short8*)&sK[(wv*16 + l16)*72 + kk*32 + quad*8];
    #pragma unroll
    for (int j=0;j<4;++j){
      short8 bb = *(const short8*)&sVt[(j*16 + l16)*72 + kk*32 + quad*8];
      accO[j] = __builtin_amdgcn_mfma_f32_16x16x32_bf16(a, bb, accO[j], 0,0,0);
    }
  }
  #pragma unroll
  for (int j=0;j<4;++j)
    #pragma unroll
    for (int rr=0;rr<4;++rr){
      int i  = wv*16 + quad*4 + rr;
      int cj = j*16 + l16;
      att[base + (size_t)i*ATT_D + cj] = f2b(accO[j][rr]);
    }
}

// ---------- residual add (+ fp32 partials + bias) + LN (optional 2nd LN) ----
__global__ __launch_bounds__(256) void add_ln_kernel(
    const float* x, const float* p, int np, const float* bias,
    const float* g, const float* bta, const float* g2, const float* b2,
    float* outf, unsigned short* outb, void* outd, const void* dsrc, int rows)
{
  int isbf = 0;
  if (dsrc) isbf = detect_isbf_block(dsrc);
  int row = blockIdx.x*4 + (threadIdx.x >> 6);
  int lane = threadIdx.x & 63;
  if (row >= rows) return;
  const float* xr = x + (size_t)row*512;
  float a[8];
  *(float4*)&a[0] = *(const float4*)(xr + lane*4);
  *(float4*)&a[4] = *(const float4*)(xr + 256 + lane*4);
  for (int s = 0; s < np; ++s){
    const float* pr = p + (size_t)s*1048576 + (size_t)row*512;
    float yb[8];
    *(float4*)&yb[0] = *(const float4*)(pr + lane*4);
    *(float4*)&yb[4] = *(const float4*)(pr + 256 + lane*4);
    #pragma unroll
    for (int e=0;e<8;++e) a[e] += yb[e];
  }
  if (bias){
    float bb2[8];
    *(float4*)&bb2[0] = *(const float4*)(bias + lane*4);
    *(float4*)&bb2[4] = *(const float4*)(bias + 256 + lane*4);
    #pragma unroll
    for (int e=0;e<8;++e) a[e] += bb2[e];
  }
  float s = 0.f, qq = 0.f;
  #pragma unroll
  for (int e=0;e<8;++e){ s += a[e]; qq += a[e]*a[e]; }
  #pragma unroll
  for (int off=32; off>0; off>>=1){
    s  += __shfl_xor(s,  off, 64);
    qq += __shfl_xor(qq, off, 64);
  }
  float mean = s * (1.f/512.f);
  float var  = qq * (1.f/512.f) - mean*mean;
  float rstd = rsqrtf(var + 1e-5f);
  float gg[8], bb[8];
  *(float4*)&gg[0] = *(const float4*)(g + lane*4);
  *(float4*)&gg[4] = *(const float4*)(g + 256 + lane*4);
  *(float4*)&bb[0] = *(const float4*)(bta + lane*4);
  *(float4*)&bb[4] = *(const float4*)(bta + 256 + lane*4);
  #pragma unroll
  for (int e=0;e<8;++e) a[e] = (a[e]-mean)*rstd*gg[e] + bb[e];
  if (g2){   // fused final encoder LN (verified in R5)
    float s2 = 0.f, q2 = 0.f;
    #pragma unroll
    for (int e=0;e<8;++e){ s2 += a[e]; q2 += a[e]*a[e]; }
    #pragma unroll
    for (int off=32; off>0; off>>=1){
      s2 += __shfl_xor(s2, off, 64);
      q2 += __shfl_xor(q2, off, 64);
    }
    float m2 = s2 * (1.f/512.f);
    float v2 = q2 * (1.f/512.f) - m2*m2;
    float r2 = rsqrtf(v2 + 1e-5f);
    float gg2[8], bb22[8];
    *(float4*)&gg2[0]  = *(const float4*)(g2 + lane*4);
    *(float4*)&gg2[4]  = *(const float4*)(g2 + 256 + lane*4);
    *(float4*)&bb22[0] = *(const float4*)(b2 + lane*4);
    *(float4*)&bb22[4] = *(const float4*)(b2 + 256 + lane*4);
    #pragma unroll
    for (int e=0;e<8;++e) a[e] = (a[e]-m2)*r2*gg2[e] + bb22[e];
  }
  if (outf){
    float* orow = outf + (size_t)row*512;
    *(float4*)(orow + lane*4)       = *(float4*)&a[0];
    *(float4*)(orow + 256 + lane*4) = *(float4*)&a[4];
  }
  if (outb){
    unsigned short* orow = outb + (size_t)row*512;
    #pragma unroll
    for (int e=0;e<4;++e){ orow[lane*4+e] = f2b(a[e]); orow[256+lane*4+e] = f2b(a[4+e]); }
  }
  if (outd){
    if (isbf){
      unsigned short* od = (unsigned short*)outd + (size_t)row*512;
      #pragma unroll
      for (int e=0;e<4;++e){ od[lane*4+e] = f2b(a[e]); od[256+lane*4+e] = f2b(a[4+e]); }
    } else {
      float* od = (float*)outd + (size_t)row*512;
      *(float4*)(od + lane*4)       = *(float4*)&a[0];
      *(float4*)(od + 256 + lane*4) = *(float4*)&a[4];
    }
  }
}

// ---------- host ----------
extern "C" void kernel_launch(void* const* d_in, const int* in_sizes, int n_in,
                              void* d_out, int out_size, void* d_ws, size_t ws_size,
                              hipStream_t stream)
{
  (void)in_sizes; (void)n_in; (void)out_size; (void)ws_size;
  const void* src = d_in[0];
  const void* Wq = d_in[1];  const void* bq = d_in[2];
  const void* Wk = d_in[3];  const void* bk = d_in[4];
  const void* Wv = d_in[5];  const void* bv = d_in[6];
  const void* Wo = d_in[7];  const void* bo = d_in[8];
  const void* W1 = d_in[9];  const void* b1 = d_in[10];
  const void* W2 = d_in[11]; const void* b2 = d_in[12];
  const void* g1 = d_in[13]; const void* be1 = d_in[14];
  const void* g2 = d_in[15]; const void* be2 = d_in[16];
  const void* gf = d_in[17]; const void* bef = d_in[18];

  char* W = (char*)d_ws;
  float* smalls          = (float*)(W + 256);        // 14336 floats (permuted layout)
  unsigned short* wt     = (unsigned short*)(W + 65536);
  float* x_f             = (float*)(W + 12648448);
  unsigned short* x_b    = (unsigned short*)(W + 16842752);
  unsigned short* q_b    = (unsigned short*)(W + 18939904);  // q,k,v contiguous (2MB each)
  unsigned short* att_b  = (unsigned short*)(W + 25231360);
  float* pp              = (float*)(W + 27328512);   // partial buffers, 4MB fp32 each
  unsigned short* h1_b   = (unsigned short*)(W + 44105728);  // 8MB
  unsigned short* k_b = q_b + 1048576;
  unsigned short* v_b = q_b + 2097152;

  // ---- combined ingest
  IngestParams ip;
  {
    const void* wsrc[6] = {Wq, Wk, Wv, Wo, W1, W2};
    int wK[6] = {512,512,512,512,512,2048};
    int wN[6] = {512,512,512,512,2048,512};
    long wsz[6] = {262144,262144,262144,262144,1048576,1048576};
    int tstart = 0; size_t dsto = 0;
    for (int l=0;l<2;++l)
      for (int ti=0;ti<6;++ti){
        int idx = l*6+ti;
        ip.w[idx].src = wsrc[ti];
        ip.w[idx].src_off = (long)l * wsz[ti];
        ip.w[idx].dst = wt + dsto;
        ip.w[idx].K = wK[ti]; ip.w[idx].N = wN[ti];
        ip.w[idx].tstart = tstart;
        tstart += (wK[ti]/32)*(wN[ti]/32);
        dsto += (size_t)wsz[ti];
      }
    const void* ss[10] = {bq,bk,bv,bo,b1,b2,g1,be1,g2,be2};
    int slen[10] = {512,512,512,512,2048,512,512,512,512,512};
    int dcur = 0, di = 0;
    for (int l=0;l<2;++l)
      for (int ti=0;ti<10;++ti){
        ip.s[di].src = ss[ti];
        ip.s[di].src_off = l * slen[ti];
        ip.s[di].dstart = dcur;
        dcur += slen[ti]; ++di;
      }
    ip.s[20].src = gf;  ip.s[20].src_off = 0; ip.s[20].dstart = dcur; dcur += 512;
    ip.s[21].src = bef; ip.s[21].src_off = 0; ip.s[21].dstart = dcur; dcur += 512;
    ip.sdst = smalls; ip.stotal = dcur;   // 14336
    ip.src = src; ip.xf = x_f; ip.xb = x_b;
    ingest_all<<<dim3(10296), 256, 0, stream>>>(ip);
  }

  for (int l = 0; l < 2; ++l){
    unsigned short* WqkvT = wt + (size_t)l*3145728;   // [1536][512]
    unsigned short* WoT   = WqkvT + 786432;           // [512][512]
    unsigned short* W1T   = WqkvT + 1048576;          // [2048][512]
    unsigned short* W2T   = WqkvT + 2097152;          // [512][2048]
    float* base  = smalls + l*6656;
    float* p_bqkv= base;           // 1536
    float* p_bo  = base + 1536;
    float* p_b1  = base + 2048;    // 2048
    float* p_b2  = base + 4096;
    float* p_g1  = base + 4608;
    float* p_be1 = base + 5120;
    float* p_g2  = base + 5632;
    float* p_be2 = base + 6144;

    // QKV: BN=128 (192 blocks; q/k/v boundaries at 512/1024 are 128-aligned)
    GemmArgs qkv = {};
    qkv.A = x_b; qkv.Bt = WqkvT; qkv.bias = p_bqkv;
    qkv.Cf = nullptr; qkv.Cb = q_b;
    qkv.K = 512; qkv.lda = 512; qkv.ldb = 512; qkv.ldc = 512;
    qkv.cshift = 9; qkv.cmask = 511; qkv.cstride = 1048576; qkv.cfz = 0; qkv.relu = 0;
    gemm_bt<128><<<dim3(12,16,1), 256, 0, stream>>>(qkv);

    // fused attention (prefix state computed redundantly per block)
    attn_kernel<<<dim3(16,16), 256, 0, stream>>>(q_b, k_b, v_b, att_b);

    // att @ Wo: K-split 2 -> fp32 partials (bias folded into LN)
    GemmArgs go = {};
    go.A = att_b; go.Bt = WoT; go.bias = nullptr;
    go.Cf = pp; go.Cb = nullptr;
    go.K = 256; go.lda = 512; go.ldb = 512; go.ldc = 512;
    go.cshift = 30; go.cmask = 0x3fffffff; go.cstride = 0; go.cfz = 1048576; go.relu = 0;
    gemm_bt<64><<<dim3(8,16,2), 256, 0, stream>>>(go);

    add_ln_kernel<<<dim3(512), 256, 0, stream>>>(x_f, pp, 2, p_bo, p_g1, p_be1,
                                                 nullptr, nullptr,
                                                 x_f, x_b, nullptr, nullptr, 2048);

    // FFN up: N=2048, bias+relu fused, bf16 out
    GemmArgs f1 = {};
    f1.A = x_b; f1.Bt = W1T; f1.bias = p_b1;
    f1.Cf = nullptr; f1.Cb = h1_b;
    f1.K = 512; f1.lda = 512; f1.ldb = 512; f1.ldc = 2048;
    f1.cshift = 30; f1.cmask = 0x3fffffff; f1.cstride = 0; f1.cfz = 0; f1.relu = 1;
    gemm_bt<128><<<dim3(16,16,1), 256, 0, stream>>>(f1);

    // FFN down: K=2048 -> K-split 2 (16 K-tiles/block)
    GemmArgs f2 = {};
    f2.A = h1_b; f2.Bt = W2T; f2.bias = nullptr;
    f2.Cf = pp; f2.Cb = nullptr;
    f2.K = 1024; f2.lda = 2048; f2.ldb = 2048; f2.ldc = 512;
    f2.cshift = 30; f2.cmask = 0x3fffffff; f2.cstride = 0; f2.cfz = 1048576; f2.relu = 0;
    gemm_bt<64><<<dim3(8,16,2), 256, 0, stream>>>(f2);

    if (l == 0){
      add_ln_kernel<<<dim3(512), 256, 0, stream>>>(x_f, pp, 2, p_b2, p_g2, p_be2,
                                                   nullptr, nullptr,
                                                   x_f, x_b, nullptr, nullptr, 2048);
    } else {
      // ln2 fused with final encoder LN -> d_out (dtype follows input)
      add_ln_kernel<<<dim3(512), 256, 0, stream>>>(x_f, pp, 2, p_b2, p_g2, p_be2,
                                                   smalls + 13312, smalls + 13824,
                                                   nullptr, nullptr, d_out, src, 2048);
    }
  }
}

// Round 8
// 257.178 us; speedup vs baseline: 3.6062x; 1.1098x over previous
//
#include <hip/hip_runtime.h>
#include <hip/hip_bf16.h>

#define DEV static __device__ __forceinline__

typedef __attribute__((ext_vector_type(8))) short short8;
typedef __attribute__((ext_vector_type(4))) float f32x4;

// ---------- helpers ----------
DEV unsigned short f2b(float f){
  unsigned int u = __float_as_uint(f);
  return (unsigned short)((u + 0x7FFFu + ((u >> 16) & 1u)) >> 16);  // RNE
}
DEV float b2f(unsigned short h){ return __uint_as_float(((unsigned int)h) << 16); }
DEV float load_in(const void* p, size_t i, int isbf){
  return isbf ? b2f(((const unsigned short*)p)[i]) : ((const float*)p)[i];
}
DEV void load_lds16(const unsigned short* g, unsigned short* l){
  __builtin_amdgcn_global_load_lds(
      (const __attribute__((address_space(1))) void*)g,
      (__attribute__((address_space(3))) void*)l, 16, 0, 0);
}

// ---------- per-block dtype detection ----------
DEV int detect_isbf_block(const void* src){
  __shared__ int cnt[4];
  int tid = threadIdx.x;
  float v = b2f(((const unsigned short*)src)[2 * tid]);
  float av = fabsf(v);
  bool sane = ((av < 64.0f) && (av > 9.5e-7f)) || (v == 0.0f);
  unsigned long long m = __ballot(sane);
  if ((tid & 63) == 0) cnt[tid >> 6] = __popcll(m);
  __syncthreads();
  int tot = cnt[0] + cnt[1] + cnt[2] + cnt[3];
  __syncthreads();
  return tot > 128;
}

// ---------- combined ingest: weights transpose + src/smalls copy ----------
struct WDesc { const void* src; long src_off; unsigned short* dst; int K; int N; int tstart; };
struct SDesc { const void* src; int src_off; int dstart; };
struct IngestParams {
  WDesc w[12];
  SDesc s[22];
  float* sdst; int stotal;
  const void* src;
  float* xf; unsigned short* xb;
};

__global__ __launch_bounds__(256) void ingest_all(IngestParams P){
  __shared__ float tile[32][33];
  int b = blockIdx.x, tid = threadIdx.x;
  int isbf = detect_isbf_block(P.src);
  if (b < 6144){
    int t = 0;
    #pragma unroll
    for (int i = 1; i < 12; ++i) if (b >= P.w[i].tstart) t = i;
    WDesc d = P.w[t];
    int r = b - d.tstart;
    int tiles_x = d.N >> 5;
    int tx = r % tiles_x, ty = r / tiles_x;
    int lx = tid & 31, ly = tid >> 5;   // 32 x 8
    #pragma unroll
    for (int i = 0; i < 4; ++i){
      int row = ty*32 + ly + i*8;
      int col = tx*32 + lx;
      tile[ly + i*8][lx] = load_in(d.src, (size_t)d.src_off + (size_t)row*d.N + col, isbf);
    }
    __syncthreads();
    #pragma unroll
    for (int i = 0; i < 4; ++i){
      int orow = tx*32 + ly + i*8;   // n
      int ocol = ty*32 + lx;         // k
      d.dst[(size_t)orow*d.K + ocol] = f2b(tile[lx][ly + i*8]);
    }
    return;
  }
  int mb = b - 6144;
  if (mb < 4096){
    int i = mb*256 + tid;
    float v = load_in(P.src, (size_t)i, isbf);
    P.xf[i] = v; P.xb[i] = f2b(v);
  } else {
    int i = (mb - 4096)*256 + tid;
    if (i < P.stotal){
      int t = 0;
      #pragma unroll
      for (int j = 1; j < 22; ++j) if (i >= P.s[j].dstart) t = j;
      P.sdst[i] = load_in(P.s[t].src, (size_t)P.s[t].src_off + (i - P.s[t].dstart), isbf);
    }
  }
}

// ---------- GEMM: C[M][N] = A[M][K] @ Bt[N][K]^T (+bias) (A,Bt bf16) ----------
// Double-buffered prefetch (round 2), XOR-swizzled LDS (round 1).
struct GemmArgs {
  const unsigned short* A;
  const unsigned short* Bt;
  const float* bias;      // nullable
  float* Cf;              // nullable (fp32 partial base)
  unsigned short* Cb;     // nullable (bf16 out)
  int K;                  // per-split K
  int lda, ldb, ldc;
  int cshift, cmask;
  size_t cstride;         // col-split stride (elements)
  size_t cfz;             // Cf z-stride (elements)
  int relu;
};

template<int BN>
__global__ __launch_bounds__(256) void gemm_bt(GemmArgs g){
  constexpr int NI = (BN == 128) ? 4 : 2;
  constexpr int NJ = 4;
  constexpr int BPASS = BN / 32;          // 32-row staging passes for B
  __shared__ __align__(16) unsigned short sA[2][128*64];
  __shared__ __align__(16) unsigned short sB[2][BN*64];
  int tid = threadIdx.x;
  int koff = blockIdx.z * g.K;
  int K = g.K, lda = g.lda, ldb = g.ldb;
  size_t bm = (size_t)blockIdx.y * 128, bn = (size_t)blockIdx.x * BN;
  int lane = tid & 63, wv = tid >> 6, quad = lane >> 4, l16 = lane & 15;
  int wm = (BN == 128) ? (wv >> 1) * 64 : wv * 32;
  int wn = (BN == 128) ? (wv & 1) * 64 : 0;
  f32x4 acc[NI][NJ];
  #pragma unroll
  for (int i=0;i<NI;++i)
    #pragma unroll
    for (int j=0;j<NJ;++j) acc[i][j] = (f32x4){0.f,0.f,0.f,0.f};
  int srow = tid >> 3;                    // 0..31 within pass
  int schunk = (tid & 7) ^ (srow & 7);
  const unsigned short* Ap = g.A  + (bm + srow)*lda + koff + schunk*8;
  const unsigned short* Bp = g.Bt + (bn + srow)*ldb + koff + schunk*8;

  #define STAGE(buf, ko)                                                      \
    do {                                                                      \
      _Pragma("unroll")                                                       \
      for (int p = 0; p < 4; ++p)                                             \
        load_lds16(Ap + (size_t)(p*32)*lda + (ko), &sA[buf][p*2048 + tid*8]); \
      _Pragma("unroll")                                                       \
      for (int p = 0; p < BPASS; ++p)                                         \
        load_lds16(Bp + (size_t)(p*32)*ldb + (ko), &sB[buf][p*2048 + tid*8]); \
    } while (0)

  STAGE(0, 0);
  asm volatile("s_waitcnt vmcnt(0)" ::: "memory");
  __builtin_amdgcn_s_barrier();

  int nt = K >> 6;
  int cur = 0;
  for (int t = 0; t < nt; ++t){
    if (t + 1 < nt){
      STAGE(cur ^ 1, (t + 1) * 64);       // issue next-tile loads early
      __builtin_amdgcn_sched_barrier(0);  // keep issue before compute
    }
    #pragma unroll
    for (int kk = 0; kk < 2; ++kk){
      short8 af[NI], bfv[NJ];
      #pragma unroll
      for (int i=0;i<NI;++i){
        int row = wm + i*16 + l16;
        int ch  = (kk*4 + quad) ^ (row & 7);
        af[i] = *(const short8*)&sA[cur][row*64 + ch*8];
      }
      #pragma unroll
      for (int j=0;j<NJ;++j){
        int row = wn + j*16 + l16;
        int ch  = (kk*4 + quad) ^ (row & 7);
        bfv[j] = *(const short8*)&sB[cur][row*64 + ch*8];
      }
      #pragma unroll
      for (int i=0;i<NI;++i)
        #pragma unroll
        for (int j=0;j<NJ;++j)
          acc[i][j] = __builtin_amdgcn_mfma_f32_16x16x32_bf16(af[i], bfv[j], acc[i][j], 0,0,0);
    }
    if (t + 1 < nt){
      asm volatile("s_waitcnt vmcnt(0)" ::: "memory");
      __builtin_amdgcn_s_barrier();
    }
    cur ^= 1;
  }
  #undef STAGE

  float* Cf = g.Cf ? g.Cf + (size_t)blockIdx.z * g.cfz : nullptr;
  unsigned short* Cb = g.Cb;
  #pragma unroll
  for (int j=0;j<NJ;++j){
    int col = (int)bn + wn + j*16 + l16;
    float bv = g.bias ? g.bias[col] : 0.f;
    size_t cbase = ((size_t)(col >> g.cshift))*g.cstride + (col & g.cmask);
    #pragma unroll
    for (int i=0;i<NI;++i){
      #pragma unroll
      for (int r=0;r<4;++r){
        int row = (int)bm + wm + i*16 + quad*4 + r;
        float v = acc[i][j][r] + bv;
        if (g.relu) v = fmaxf(v, 0.f);
        size_t idx = cbase + (size_t)row*g.ldc;
        if (Cf) Cf[idx] = v;
        if (Cb) Cb[idx] = f2b(v);
      }
    }
  }
}

// ---------- chunked causal linear attention, parallel over (bh, chunk) ----------
#define ATT_S 1024
#define ATT_D 512

// Pass A: states[bh][c] = V_c^T K_c   (64x64 fp32)
__global__ __launch_bounds__(256) void attn_state_kernel(
    const unsigned short* k, const unsigned short* v, float* states)
{
  __shared__ __align__(16) unsigned short sVt[64*72];
  __shared__ __align__(16) unsigned short sKt[64*72];
  int tid = threadIdx.x;
  int c = blockIdx.x, bh = blockIdx.y;
  int b = bh >> 3, h = bh & 7;
  const size_t base = ((size_t)b*ATT_S + (size_t)c*64)*ATT_D + h*64;
  int lane = tid & 63, wv = tid >> 6, quad = lane >> 4, l16 = lane & 15;

  int t = lane, vc = wv*8;
  const unsigned short* vp = v + base + (size_t)t*ATT_D;
  const unsigned short* kp = k + base + (size_t)t*ATT_D;
  float4 v0 = *(const float4*)(vp + vc);
  float4 v1 = *(const float4*)(vp + vc + 32);
  float4 k0 = *(const float4*)(kp + vc);
  float4 k1 = *(const float4*)(kp + vc + 32);
  {
    const unsigned short* pv0 = (const unsigned short*)&v0;
    const unsigned short* pv1 = (const unsigned short*)&v1;
    const unsigned short* pk0 = (const unsigned short*)&k0;
    const unsigned short* pk1 = (const unsigned short*)&k1;
    #pragma unroll
    for (int e = 0; e < 8; ++e){
      sVt[(vc+e)*72 + t]    = pv0[e];
      sVt[(vc+32+e)*72 + t] = pv1[e];
      sKt[(vc+e)*72 + t]    = pk0[e];
      sKt[(vc+32+e)*72 + t] = pk1[e];
    }
  }
  __syncthreads();

  f32x4 acc[4];
  #pragma unroll
  for (int j=0;j<4;++j) acc[j] = (f32x4){0.f,0.f,0.f,0.f};
  #pragma unroll
  for (int kk=0;kk<2;++kk){
    short8 a = *(const short8*)&sVt[(wv*16 + l16)*72 + kk*32 + quad*8];
    #pragma unroll
    for (int j=0;j<4;++j){
      short8 bb = *(const short8*)&sKt[(j*16 + l16)*72 + kk*32 + quad*8];
      acc[j] = __builtin_amdgcn_mfma_f32_16x16x32_bf16(a, bb, acc[j], 0,0,0);
    }
  }
  float* st = states + ((size_t)bh*16 + c)*4096;
  #pragma unroll
  for (int j=0;j<4;++j)
    #pragma unroll
    for (int rr=0;rr<4;++rr)
      st[(wv*16 + quad*4 + rr)*64 + j*16 + l16] = acc[j][rr];
}

// Pass B: att_c = Q_c @ (sum_{cc<c} states[cc]) + tril(Q_c K_c^T) @ V_c
__global__ __launch_bounds__(256) void attn_out_kernel(
    const unsigned short* q, const unsigned short* k, const unsigned short* v,
    const float* states, unsigned short* att)
{
  __shared__ __align__(16) unsigned short sQ [64*72];
  __shared__ __align__(16) unsigned short sK [64*72];   // K chunk, reused for S
  __shared__ __align__(16) unsigned short sVt[64*72];
  __shared__ __align__(16) float sKV[64*68];
  int tid = threadIdx.x;
  int c = blockIdx.x, bh = blockIdx.y;
  int b = bh >> 3, h = bh & 7;
  const size_t base = ((size_t)b*ATT_S + (size_t)c*64)*ATT_D + h*64;
  int lane = tid & 63, wv = tid >> 6, quad = lane >> 4, l16 = lane & 15;

  // exclusive prefix sum of chunk states (fp32)
  float4 racc[4];
  #pragma unroll
  for (int u=0;u<4;++u) racc[u] = (float4){0.f,0.f,0.f,0.f};
  const float* sbase = states + (size_t)bh*16*4096;
  for (int cc = 0; cc < c; ++cc){
    const float4* sp = (const float4*)(sbase + (size_t)cc*4096);
    #pragma unroll
    for (int u=0;u<4;++u){
      float4 t4 = sp[tid + u*256];
      racc[u].x += t4.x; racc[u].y += t4.y; racc[u].z += t4.z; racc[u].w += t4.w;
    }
  }
  #pragma unroll
  for (int u=0;u<4;++u){
    int e = (tid + u*256)*4;
    int row = e >> 6, col = e & 63;
    *(float4*)&sKV[row*68 + col] = racc[u];
  }

  // stage Q, K row-major; V transposed
  int r = tid >> 2, c8 = (tid & 3)*8;
  const unsigned short* qp = q + base + (size_t)r*ATT_D;
  const unsigned short* kp = k + base + (size_t)r*ATT_D;
  float4 q0 = *(const float4*)(qp + c8);
  float4 q1 = *(const float4*)(qp + c8 + 32);
  float4 k0 = *(const float4*)(kp + c8);
  float4 k1 = *(const float4*)(kp + c8 + 32);
  int t = lane, vc = wv*8;
  const unsigned short* vp = v + base + (size_t)t*ATT_D;
  float4 v0 = *(const float4*)(vp + vc);
  float4 v1 = *(const float4*)(vp + vc + 32);
  *(float4*)&sQ[r*72 + c8]      = q0;
  *(float4*)&sQ[r*72 + c8 + 32] = q1;
  *(float4*)&sK[r*72 + c8]      = k0;
  *(float4*)&sK[r*72 + c8 + 32] = k1;
  {
    const unsigned short* pv0 = (const unsigned short*)&v0;
    const unsigned short* pv1 = (const unsigned short*)&v1;
    #pragma unroll
    for (int e=0;e<8;++e){
      sVt[(vc+e)*72 + t]    = pv0[e];
      sVt[(vc+32+e)*72 + t] = pv1[e];
    }
  }
  __syncthreads();

  // S = Q K^T
  f32x4 accS[4];
  #pragma unroll
  for (int j=0;j<4;++j) accS[j] = (f32x4){0.f,0.f,0.f,0.f};
  #pragma unroll
  for (int kk=0;kk<2;++kk){
    short8 a = *(const short8*)&sQ[(wv*16 + l16)*72 + kk*32 + quad*8];
    #pragma unroll
    for (int j=0;j<4;++j){
      short8 bb = *(const short8*)&sK[(j*16 + l16)*72 + kk*32 + quad*8];
      accS[j] = __builtin_amdgcn_mfma_f32_16x16x32_bf16(a, bb, accS[j], 0,0,0);
    }
  }
  __syncthreads();   // all waves done reading sK

  // masked S -> sK (bf16)
  #pragma unroll
  for (int j=0;j<4;++j)
    #pragma unroll
    for (int rr=0;rr<4;++rr){
      int i  = wv*16 + quad*4 + rr;
      int cj = j*16 + l16;
      sK[i*72 + cj] = f2b((i >= cj) ? accS[j][rr] : 0.f);
    }

  // att = Q @ KV_prefix (state converted bf16 on the fly)
  f32x4 accO[4];
  #pragma unroll
  for (int j=0;j<4;++j) accO[j] = (f32x4){0.f,0.f,0.f,0.f};
  #pragma unroll
  for (int kk=0;kk<2;++kk){
    short8 a = *(const short8*)&sQ[(wv*16 + l16)*72 + kk*32 + quad*8];
    #pragma unroll
    for (int j=0;j<4;++j){
      const float* pf = &sKV[(j*16 + l16)*68 + kk*32 + quad*8];
      short8 bb;
      #pragma unroll
      for (int e=0;e<8;++e) ((unsigned short*)&bb)[e] = f2b(pf[e]);
      accO[j] = __builtin_amdgcn_mfma_f32_16x16x32_bf16(a, bb, accO[j], 0,0,0);
    }
  }
  __syncthreads();   // S visible to all waves

  // att += S @ V
  #pragma unroll
  for (int kk=0;kk<2;++kk){
    short8 a = *(const short8*)&sK[(wv*16 + l16)*72 + kk*32 + quad*8];
    #pragma unroll
    for (int j=0;j<4;++j){
      short8 bb = *(const short8*)&sVt[(j*16 + l16)*72 + kk*32 + quad*8];
      accO[j] = __builtin_amdgcn_mfma_f32_16x16x32_bf16(a, bb, accO[j], 0,0,0);
    }
  }
  #pragma unroll
  for (int j=0;j<4;++j)
    #pragma unroll
    for (int rr=0;rr<4;++rr){
      int i  = wv*16 + quad*4 + rr;
      int cj = j*16 + l16;
      att[base + (size_t)i*ATT_D + cj] = f2b(accO[j][rr]);
    }
}

// ---------- residual add (+ fp32 partials + bias) + LN (optional 2nd LN) ----
__global__ __launch_bounds__(256) void add_ln_kernel(
    const float* x, const float* p, int np, const float* bias,
    const float* g, const float* bta, const float* g2, const float* b2,
    float* outf, unsigned short* outb, void* outd, const void* dsrc, int rows)
{
  int isbf = 0;
  if (dsrc) isbf = detect_isbf_block(dsrc);
  int row = blockIdx.x*4 + (threadIdx.x >> 6);
  int lane = threadIdx.x & 63;
  if (row >= rows) return;
  const float* xr = x + (size_t)row*512;
  float a[8];
  *(float4*)&a[0] = *(const float4*)(xr + lane*4);
  *(float4*)&a[4] = *(const float4*)(xr + 256 + lane*4);
  for (int s = 0; s < np; ++s){
    const float* pr = p + (size_t)s*1048576 + (size_t)row*512;
    float yb[8];
    *(float4*)&yb[0] = *(const float4*)(pr + lane*4);
    *(float4*)&yb[4] = *(const float4*)(pr + 256 + lane*4);
    #pragma unroll
    for (int e=0;e<8;++e) a[e] += yb[e];
  }
  if (bias){
    float bb2[8];
    *(float4*)&bb2[0] = *(const float4*)(bias + lane*4);
    *(float4*)&bb2[4] = *(const float4*)(bias + 256 + lane*4);
    #pragma unroll
    for (int e=0;e<8;++e) a[e] += bb2[e];
  }
  float s = 0.f, qq = 0.f;
  #pragma unroll
  for (int e=0;e<8;++e){ s += a[e]; qq += a[e]*a[e]; }
  #pragma unroll
  for (int off=32; off>0; off>>=1){
    s  += __shfl_xor(s,  off, 64);
    qq += __shfl_xor(qq, off, 64);
  }
  float mean = s * (1.f/512.f);
  float var  = qq * (1.f/512.f) - mean*mean;
  float rstd = rsqrtf(var + 1e-5f);
  float gg[8], bb[8];
  *(float4*)&gg[0] = *(const float4*)(g + lane*4);
  *(float4*)&gg[4] = *(const float4*)(g + 256 + lane*4);
  *(float4*)&bb[0] = *(const float4*)(bta + lane*4);
  *(float4*)&bb[4] = *(const float4*)(bta + 256 + lane*4);
  #pragma unroll
  for (int e=0;e<8;++e) a[e] = (a[e]-mean)*rstd*gg[e] + bb[e];
  if (g2){   // fused final encoder LN (verified R5/R7)
    float s2 = 0.f, q2 = 0.f;
    #pragma unroll
    for (int e=0;e<8;++e){ s2 += a[e]; q2 += a[e]*a[e]; }
    #pragma unroll
    for (int off=32; off>0; off>>=1){
      s2 += __shfl_xor(s2, off, 64);
      q2 += __shfl_xor(q2, off, 64);
    }
    float m2 = s2 * (1.f/512.f);
    float v2 = q2 * (1.f/512.f) - m2*m2;
    float r2 = rsqrtf(v2 + 1e-5f);
    float gg2[8], bb22[8];
    *(float4*)&gg2[0]  = *(const float4*)(g2 + lane*4);
    *(float4*)&gg2[4]  = *(const float4*)(g2 + 256 + lane*4);
    *(float4*)&bb22[0] = *(const float4*)(b2 + lane*4);
    *(float4*)&bb22[4] = *(const float4*)(b2 + 256 + lane*4);
    #pragma unroll
    for (int e=0;e<8;++e) a[e] = (a[e]-m2)*r2*gg2[e] + bb22[e];
  }
  if (outf){
    float* orow = outf + (size_t)row*512;
    *(float4*)(orow + lane*4)       = *(float4*)&a[0];
    *(float4*)(orow + 256 + lane*4) = *(float4*)&a[4];
  }
  if (outb){
    unsigned short* orow = outb + (size_t)row*512;
    #pragma unroll
    for (int e=0;e<4;++e){ orow[lane*4+e] = f2b(a[e]); orow[256+lane*4+e] = f2b(a[4+e]); }
  }
  if (outd){
    if (isbf){
      unsigned short* od = (unsigned short*)outd + (size_t)row*512;
      #pragma unroll
      for (int e=0;e<4;++e){ od[lane*4+e] = f2b(a[e]); od[256+lane*4+e] = f2b(a[4+e]); }
    } else {
      float* od = (float*)outd + (size_t)row*512;
      *(float4*)(od + lane*4)       = *(float4*)&a[0];
      *(float4*)(od + 256 + lane*4) = *(float4*)&a[4];
    }
  }
}

// ---------- host ----------
extern "C" void kernel_launch(void* const* d_in, const int* in_sizes, int n_in,
                              void* d_out, int out_size, void* d_ws, size_t ws_size,
                              hipStream_t stream)
{
  (void)in_sizes; (void)n_in; (void)out_size; (void)ws_size;
  const void* src = d_in[0];
  const void* Wq = d_in[1];  const void* bq = d_in[2];
  const void* Wk = d_in[3];  const void* bk = d_in[4];
  const void* Wv = d_in[5];  const void* bv = d_in[6];
  const void* Wo = d_in[7];  const void* bo = d_in[8];
  const void* W1 = d_in[9];  const void* b1 = d_in[10];
  const void* W2 = d_in[11]; const void* b2 = d_in[12];
  const void* g1 = d_in[13]; const void* be1 = d_in[14];
  const void* g2 = d_in[15]; const void* be2 = d_in[16];
  const void* gf = d_in[17]; const void* bef = d_in[18];

  char* W = (char*)d_ws;
  float* smalls          = (float*)(W + 256);        // 14336 floats (permuted layout)
  unsigned short* wt     = (unsigned short*)(W + 65536);
  float* x_f             = (float*)(W + 12648448);
  unsigned short* x_b    = (unsigned short*)(W + 16842752);
  unsigned short* q_b    = (unsigned short*)(W + 18939904);  // q,k,v contiguous (2MB each)
  unsigned short* att_b  = (unsigned short*)(W + 25231360);
  float* pp              = (float*)(W + 27328512);   // partial buffers, 4MB fp32 each
  unsigned short* h1_b   = (unsigned short*)(W + 44105728);  // 8MB
  float* states          = (float*)(W + 44105728);   // aliases h1_b (disjoint lifetime)
  unsigned short* k_b = q_b + 1048576;
  unsigned short* v_b = q_b + 2097152;

  // ---- combined ingest
  IngestParams ip;
  {
    const void* wsrc[6] = {Wq, Wk, Wv, Wo, W1, W2};
    int wK[6] = {512,512,512,512,512,2048};
    int wN[6] = {512,512,512,512,2048,512};
    long wsz[6] = {262144,262144,262144,262144,1048576,1048576};
    int tstart = 0; size_t dsto = 0;
    for (int l=0;l<2;++l)
      for (int ti=0;ti<6;++ti){
        int idx = l*6+ti;
        ip.w[idx].src = wsrc[ti];
        ip.w[idx].src_off = (long)l * wsz[ti];
        ip.w[idx].dst = wt + dsto;
        ip.w[idx].K = wK[ti]; ip.w[idx].N = wN[ti];
        ip.w[idx].tstart = tstart;
        tstart += (wK[ti]/32)*(wN[ti]/32);
        dsto += (size_t)wsz[ti];
      }
    const void* ss[10] = {bq,bk,bv,bo,b1,b2,g1,be1,g2,be2};
    int slen[10] = {512,512,512,512,2048,512,512,512,512,512};
    int dcur = 0, di = 0;
    for (int l=0;l<2;++l)
      for (int ti=0;ti<10;++ti){
        ip.s[di].src = ss[ti];
        ip.s[di].src_off = l * slen[ti];
        ip.s[di].dstart = dcur;
        dcur += slen[ti]; ++di;
      }
    ip.s[20].src = gf;  ip.s[20].src_off = 0; ip.s[20].dstart = dcur; dcur += 512;
    ip.s[21].src = bef; ip.s[21].src_off = 0; ip.s[21].dstart = dcur; dcur += 512;
    ip.sdst = smalls; ip.stotal = dcur;   // 14336
    ip.src = src; ip.xf = x_f; ip.xb = x_b;
    ingest_all<<<dim3(10296), 256, 0, stream>>>(ip);
  }

  for (int l = 0; l < 2; ++l){
    unsigned short* WqkvT = wt + (size_t)l*3145728;   // [1536][512]
    unsigned short* WoT   = WqkvT + 786432;           // [512][512]
    unsigned short* W1T   = WqkvT + 1048576;          // [2048][512]
    unsigned short* W2T   = WqkvT + 2097152;          // [512][2048]
    float* base  = smalls + l*6656;
    float* p_bqkv= base;           // 1536
    float* p_bo  = base + 1536;
    float* p_b1  = base + 2048;    // 2048
    float* p_b2  = base + 4096;
    float* p_g1  = base + 4608;
    float* p_be1 = base + 5120;
    float* p_g2  = base + 5632;
    float* p_be2 = base + 6144;

    // QKV: one GEMM, N=1536, BN=64 (R4-proven)
    GemmArgs qkv = {};
    qkv.A = x_b; qkv.Bt = WqkvT; qkv.bias = p_bqkv;
    qkv.Cf = nullptr; qkv.Cb = q_b;
    qkv.K = 512; qkv.lda = 512; qkv.ldb = 512; qkv.ldc = 512;
    qkv.cshift = 9; qkv.cmask = 511; qkv.cstride = 1048576; qkv.cfz = 0; qkv.relu = 0;
    gemm_bt<64><<<dim3(24,16,1), 256, 0, stream>>>(qkv);

    attn_state_kernel<<<dim3(16,16), 256, 0, stream>>>(k_b, v_b, states);
    attn_out_kernel<<<dim3(16,16), 256, 0, stream>>>(q_b, k_b, v_b, states, att_b);

    // att @ Wo: K-split 2 -> fp32 partials (bias folded into LN)
    GemmArgs go = {};
    go.A = att_b; go.Bt = WoT; go.bias = nullptr;
    go.Cf = pp; go.Cb = nullptr;
    go.K = 256; go.lda = 512; go.ldb = 512; go.ldc = 512;
    go.cshift = 30; go.cmask = 0x3fffffff; go.cstride = 0; go.cfz = 1048576; go.relu = 0;
    gemm_bt<64><<<dim3(8,16,2), 256, 0, stream>>>(go);

    add_ln_kernel<<<dim3(512), 256, 0, stream>>>(x_f, pp, 2, p_bo, p_g1, p_be1,
                                                 nullptr, nullptr,
                                                 x_f, x_b, nullptr, nullptr, 2048);

    // FFN up: BN=64, grid (32,16) = 512 blocks = 2 blocks/CU (48KB LDS both
    // resident) -> second block's waves compute through this block's
    // vmcnt-drain barrier stall (m114 wave-level overlap; absent at 1/CU).
    GemmArgs f1 = {};
    f1.A = x_b; f1.Bt = W1T; f1.bias = p_b1;
    f1.Cf = nullptr; f1.Cb = h1_b;
    f1.K = 512; f1.lda = 512; f1.ldb = 512; f1.ldc = 2048;
    f1.cshift = 30; f1.cmask = 0x3fffffff; f1.cstride = 0; f1.cfz = 0; f1.relu = 1;
    gemm_bt<64><<<dim3(32,16,1), 256, 0, stream>>>(f1);

    // FFN down: K=2048 -> K-split 2 (16 K-tiles/block)
    GemmArgs f2 = {};
    f2.A = h1_b; f2.Bt = W2T; f2.bias = nullptr;
    f2.Cf = pp; f2.Cb = nullptr;
    f2.K = 1024; f2.lda = 2048; f2.ldb = 2048; f2.ldc = 512;
    f2.cshift = 30; f2.cmask = 0x3fffffff; f2.cstride = 0; f2.cfz = 1048576; f2.relu = 0;
    gemm_bt<64><<<dim3(8,16,2), 256, 0, stream>>>(f2);

    if (l == 0){
      add_ln_kernel<<<dim3(512), 256, 0, stream>>>(x_f, pp, 2, p_b2, p_g2, p_be2,
                                                   nullptr, nullptr,
                                                   x_f, x_b, nullptr, nullptr, 2048);
    } else {
      // ln2 fused with final encoder LN -> d_out (dtype follows input)
      add_ln_kernel<<<dim3(512), 256, 0, stream>>>(x_f, pp, 2, p_b2, p_g2, p_be2,
                                                   smalls + 13312, smalls + 13824,
                                                   nullptr, nullptr, d_out, src, 2048);
    }
  }
}

// Round 9
// 253.417 us; speedup vs baseline: 3.6597x; 1.0148x over previous
//
#include <hip/hip_runtime.h>
#include <hip/hip_bf16.h>

#define DEV static __device__ __forceinline__

typedef __attribute__((ext_vector_type(8))) short short8;
typedef __attribute__((ext_vector_type(4))) float f32x4;

// ---------- helpers ----------
DEV unsigned short f2b(float f){
  unsigned int u = __float_as_uint(f);
  return (unsigned short)((u + 0x7FFFu + ((u >> 16) & 1u)) >> 16);  // RNE
}
DEV float b2f(unsigned short h){ return __uint_as_float(((unsigned int)h) << 16); }
DEV float load_in(const void* p, size_t i, int isbf){
  return isbf ? b2f(((const unsigned short*)p)[i]) : ((const float*)p)[i];
}
DEV void load_lds16(const unsigned short* g, unsigned short* l){
  __builtin_amdgcn_global_load_lds(
      (const __attribute__((address_space(1))) void*)g,
      (__attribute__((address_space(3))) void*)l, 16, 0, 0);
}

// ---------- per-block dtype detection ----------
DEV int detect_isbf_block(const void* src){
  __shared__ int cnt[4];
  int tid = threadIdx.x;
  float v = b2f(((const unsigned short*)src)[2 * tid]);
  float av = fabsf(v);
  bool sane = ((av < 64.0f) && (av > 9.5e-7f)) || (v == 0.0f);
  unsigned long long m = __ballot(sane);
  if ((tid & 63) == 0) cnt[tid >> 6] = __popcll(m);
  __syncthreads();
  int tot = cnt[0] + cnt[1] + cnt[2] + cnt[3];
  __syncthreads();
  return tot > 128;
}

// ---------- combined ingest: weights transpose + src bf16 + smalls ----------
// x_f copy dropped (R9): layer-0 ln1 reads src directly via isbf path.
struct WDesc { const void* src; long src_off; unsigned short* dst; int K; int N; int tstart; };
struct SDesc { const void* src; int src_off; int dstart; };
struct IngestParams {
  WDesc w[12];
  SDesc s[22];
  float* sdst; int stotal;
  const void* src;
  unsigned short* xb;
};

__global__ __launch_bounds__(256) void ingest_all(IngestParams P){
  __shared__ float tile[32][33];
  int b = blockIdx.x, tid = threadIdx.x;
  int isbf = detect_isbf_block(P.src);
  if (b < 6144){
    int t = 0;
    #pragma unroll
    for (int i = 1; i < 12; ++i) if (b >= P.w[i].tstart) t = i;
    WDesc d = P.w[t];
    int r = b - d.tstart;
    int tiles_x = d.N >> 5;
    int tx = r % tiles_x, ty = r / tiles_x;
    int lx = tid & 31, ly = tid >> 5;   // 32 x 8
    #pragma unroll
    for (int i = 0; i < 4; ++i){
      int row = ty*32 + ly + i*8;
      int col = tx*32 + lx;
      tile[ly + i*8][lx] = load_in(d.src, (size_t)d.src_off + (size_t)row*d.N + col, isbf);
    }
    __syncthreads();
    #pragma unroll
    for (int i = 0; i < 4; ++i){
      int orow = tx*32 + ly + i*8;   // n
      int ocol = ty*32 + lx;         // k
      d.dst[(size_t)orow*d.K + ocol] = f2b(tile[lx][ly + i*8]);
    }
    return;
  }
  int mb = b - 6144;
  if (mb < 4096){
    int i = mb*256 + tid;
    P.xb[i] = f2b(load_in(P.src, (size_t)i, isbf));
  } else {
    int i = (mb - 4096)*256 + tid;
    if (i < P.stotal){
      int t = 0;
      #pragma unroll
      for (int j = 1; j < 22; ++j) if (i >= P.s[j].dstart) t = j;
      P.sdst[i] = load_in(P.s[t].src, (size_t)P.s[t].src_off + (i - P.s[t].dstart), isbf);
    }
  }
}

// ---------- GEMM: C[M][N] = A[M][K] @ Bt[N][K]^T (+bias) (A,Bt bf16) ----------
// Double-buffered prefetch (round 2), XOR-swizzled LDS (round 1).
struct GemmArgs {
  const unsigned short* A;
  const unsigned short* Bt;
  const float* bias;      // nullable
  float* Cf;              // nullable (fp32 partial base)
  unsigned short* Cb;     // nullable (bf16 out)
  int K;                  // per-split K
  int lda, ldb, ldc;
  int cshift, cmask;
  size_t cstride;         // col-split stride (elements)
  size_t cfz;             // Cf z-stride (elements)
  int relu;
};

template<int BN>
__global__ __launch_bounds__(256) void gemm_bt(GemmArgs g){
  constexpr int NI = (BN == 128) ? 4 : 2;
  constexpr int NJ = 4;
  constexpr int BPASS = BN / 32;          // 32-row staging passes for B
  __shared__ __align__(16) unsigned short sA[2][128*64];
  __shared__ __align__(16) unsigned short sB[2][BN*64];
  int tid = threadIdx.x;
  int koff = blockIdx.z * g.K;
  int K = g.K, lda = g.lda, ldb = g.ldb;
  size_t bm = (size_t)blockIdx.y * 128, bn = (size_t)blockIdx.x * BN;
  int lane = tid & 63, wv = tid >> 6, quad = lane >> 4, l16 = lane & 15;
  int wm = (BN == 128) ? (wv >> 1) * 64 : wv * 32;
  int wn = (BN == 128) ? (wv & 1) * 64 : 0;
  f32x4 acc[NI][NJ];
  #pragma unroll
  for (int i=0;i<NI;++i)
    #pragma unroll
    for (int j=0;j<NJ;++j) acc[i][j] = (f32x4){0.f,0.f,0.f,0.f};
  int srow = tid >> 3;                    // 0..31 within pass
  int schunk = (tid & 7) ^ (srow & 7);
  const unsigned short* Ap = g.A  + (bm + srow)*lda + koff + schunk*8;
  const unsigned short* Bp = g.Bt + (bn + srow)*ldb + koff + schunk*8;

  #define STAGE(buf, ko)                                                      \
    do {                                                                      \
      _Pragma("unroll")                                                       \
      for (int p = 0; p < 4; ++p)                                             \
        load_lds16(Ap + (size_t)(p*32)*lda + (ko), &sA[buf][p*2048 + tid*8]); \
      _Pragma("unroll")                                                       \
      for (int p = 0; p < BPASS; ++p)                                         \
        load_lds16(Bp + (size_t)(p*32)*ldb + (ko), &sB[buf][p*2048 + tid*8]); \
    } while (0)

  STAGE(0, 0);
  asm volatile("s_waitcnt vmcnt(0)" ::: "memory");
  __builtin_amdgcn_s_barrier();

  int nt = K >> 6;
  int cur = 0;
  for (int t = 0; t < nt; ++t){
    if (t + 1 < nt){
      STAGE(cur ^ 1, (t + 1) * 64);       // issue next-tile loads early
      __builtin_amdgcn_sched_barrier(0);  // keep issue before compute
    }
    #pragma unroll
    for (int kk = 0; kk < 2; ++kk){
      short8 af[NI], bfv[NJ];
      #pragma unroll
      for (int i=0;i<NI;++i){
        int row = wm + i*16 + l16;
        int ch  = (kk*4 + quad) ^ (row & 7);
        af[i] = *(const short8*)&sA[cur][row*64 + ch*8];
      }
      #pragma unroll
      for (int j=0;j<NJ;++j){
        int row = wn + j*16 + l16;
        int ch  = (kk*4 + quad) ^ (row & 7);
        bfv[j] = *(const short8*)&sB[cur][row*64 + ch*8];
      }
      #pragma unroll
      for (int i=0;i<NI;++i)
        #pragma unroll
        for (int j=0;j<NJ;++j)
          acc[i][j] = __builtin_amdgcn_mfma_f32_16x16x32_bf16(af[i], bfv[j], acc[i][j], 0,0,0);
    }
    if (t + 1 < nt){
      asm volatile("s_waitcnt vmcnt(0)" ::: "memory");
      __builtin_amdgcn_s_barrier();
    }
    cur ^= 1;
  }
  #undef STAGE

  float* Cf = g.Cf ? g.Cf + (size_t)blockIdx.z * g.cfz : nullptr;
  unsigned short* Cb = g.Cb;
  #pragma unroll
  for (int j=0;j<NJ;++j){
    int col = (int)bn + wn + j*16 + l16;
    float bv = g.bias ? g.bias[col] : 0.f;
    size_t cbase = ((size_t)(col >> g.cshift))*g.cstride + (col & g.cmask);
    #pragma unroll
    for (int i=0;i<NI;++i){
      #pragma unroll
      for (int r=0;r<4;++r){
        int row = (int)bm + wm + i*16 + quad*4 + r;
        float v = acc[i][j][r] + bv;
        if (g.relu) v = fmaxf(v, 0.f);
        size_t idx = cbase + (size_t)row*g.ldc;
        if (Cf) Cf[idx] = v;
        if (Cb) Cb[idx] = f2b(v);
      }
    }
  }
}

// ---------- chunked causal linear attention, parallel over (bh, chunk) ----------
#define ATT_S 1024
#define ATT_D 512

// Pass A: states[bh][c] = V_c^T K_c   (64x64 fp32)
__global__ __launch_bounds__(256) void attn_state_kernel(
    const unsigned short* k, const unsigned short* v, float* states)
{
  __shared__ __align__(16) unsigned short sVt[64*72];
  __shared__ __align__(16) unsigned short sKt[64*72];
  int tid = threadIdx.x;
  int c = blockIdx.x, bh = blockIdx.y;
  int b = bh >> 3, h = bh & 7;
  const size_t base = ((size_t)b*ATT_S + (size_t)c*64)*ATT_D + h*64;
  int lane = tid & 63, wv = tid >> 6, quad = lane >> 4, l16 = lane & 15;

  int t = lane, vc = wv*8;
  const unsigned short* vp = v + base + (size_t)t*ATT_D;
  const unsigned short* kp = k + base + (size_t)t*ATT_D;
  float4 v0 = *(const float4*)(vp + vc);
  float4 v1 = *(const float4*)(vp + vc + 32);
  float4 k0 = *(const float4*)(kp + vc);
  float4 k1 = *(const float4*)(kp + vc + 32);
  {
    const unsigned short* pv0 = (const unsigned short*)&v0;
    const unsigned short* pv1 = (const unsigned short*)&v1;
    const unsigned short* pk0 = (const unsigned short*)&k0;
    const unsigned short* pk1 = (const unsigned short*)&k1;
    #pragma unroll
    for (int e = 0; e < 8; ++e){
      sVt[(vc+e)*72 + t]    = pv0[e];
      sVt[(vc+32+e)*72 + t] = pv1[e];
      sKt[(vc+e)*72 + t]    = pk0[e];
      sKt[(vc+32+e)*72 + t] = pk1[e];
    }
  }
  __syncthreads();

  f32x4 acc[4];
  #pragma unroll
  for (int j=0;j<4;++j) acc[j] = (f32x4){0.f,0.f,0.f,0.f};
  #pragma unroll
  for (int kk=0;kk<2;++kk){
    short8 a = *(const short8*)&sVt[(wv*16 + l16)*72 + kk*32 + quad*8];
    #pragma unroll
    for (int j=0;j<4;++j){
      short8 bb = *(const short8*)&sKt[(j*16 + l16)*72 + kk*32 + quad*8];
      acc[j] = __builtin_amdgcn_mfma_f32_16x16x32_bf16(a, bb, acc[j], 0,0,0);
    }
  }
  float* st = states + ((size_t)bh*16 + c)*4096;
  #pragma unroll
  for (int j=0;j<4;++j)
    #pragma unroll
    for (int rr=0;rr<4;++rr)
      st[(wv*16 + quad*4 + rr)*64 + j*16 + l16] = acc[j][rr];
}

// Pass B: att_c = Q_c @ (sum_{cc<c} states[cc]) + tril(Q_c K_c^T) @ V_c
__global__ __launch_bounds__(256) void attn_out_kernel(
    const unsigned short* q, const unsigned short* k, const unsigned short* v,
    const float* states, unsigned short* att)
{
  __shared__ __align__(16) unsigned short sQ [64*72];
  __shared__ __align__(16) unsigned short sK [64*72];   // K chunk, reused for S
  __shared__ __align__(16) unsigned short sVt[64*72];
  __shared__ __align__(16) float sKV[64*68];
  int tid = threadIdx.x;
  int c = blockIdx.x, bh = blockIdx.y;
  int b = bh >> 3, h = bh & 7;
  const size_t base = ((size_t)b*ATT_S + (size_t)c*64)*ATT_D + h*64;
  int lane = tid & 63, wv = tid >> 6, quad = lane >> 4, l16 = lane & 15;

  // exclusive prefix sum of chunk states (fp32)
  float4 racc[4];
  #pragma unroll
  for (int u=0;u<4;++u) racc[u] = (float4){0.f,0.f,0.f,0.f};
  const float* sbase = states + (size_t)bh*16*4096;
  for (int cc = 0; cc < c; ++cc){
    const float4* sp = (const float4*)(sbase + (size_t)cc*4096);
    #pragma unroll
    for (int u=0;u<4;++u){
      float4 t4 = sp[tid + u*256];
      racc[u].x += t4.x; racc[u].y += t4.y; racc[u].z += t4.z; racc[u].w += t4.w;
    }
  }
  #pragma unroll
  for (int u=0;u<4;++u){
    int e = (tid + u*256)*4;
    int row = e >> 6, col = e & 63;
    *(float4*)&sKV[row*68 + col] = racc[u];
  }

  // stage Q, K row-major; V transposed
  int r = tid >> 2, c8 = (tid & 3)*8;
  const unsigned short* qp = q + base + (size_t)r*ATT_D;
  const unsigned short* kp = k + base + (size_t)r*ATT_D;
  float4 q0 = *(const float4*)(qp + c8);
  float4 q1 = *(const float4*)(qp + c8 + 32);
  float4 k0 = *(const float4*)(kp + c8);
  float4 k1 = *(const float4*)(kp + c8 + 32);
  int t = lane, vc = wv*8;
  const unsigned short* vp = v + base + (size_t)t*ATT_D;
  float4 v0 = *(const float4*)(vp + vc);
  float4 v1 = *(const float4*)(vp + vc + 32);
  *(float4*)&sQ[r*72 + c8]      = q0;
  *(float4*)&sQ[r*72 + c8 + 32] = q1;
  *(float4*)&sK[r*72 + c8]      = k0;
  *(float4*)&sK[r*72 + c8 + 32] = k1;
  {
    const unsigned short* pv0 = (const unsigned short*)&v0;
    const unsigned short* pv1 = (const unsigned short*)&v1;
    #pragma unroll
    for (int e=0;e<8;++e){
      sVt[(vc+e)*72 + t]    = pv0[e];
      sVt[(vc+32+e)*72 + t] = pv1[e];
    }
  }
  __syncthreads();

  // S = Q K^T
  f32x4 accS[4];
  #pragma unroll
  for (int j=0;j<4;++j) accS[j] = (f32x4){0.f,0.f,0.f,0.f};
  #pragma unroll
  for (int kk=0;kk<2;++kk){
    short8 a = *(const short8*)&sQ[(wv*16 + l16)*72 + kk*32 + quad*8];
    #pragma unroll
    for (int j=0;j<4;++j){
      short8 bb = *(const short8*)&sK[(j*16 + l16)*72 + kk*32 + quad*8];
      accS[j] = __builtin_amdgcn_mfma_f32_16x16x32_bf16(a, bb, accS[j], 0,0,0);
    }
  }
  __syncthreads();   // all waves done reading sK

  // masked S -> sK (bf16)
  #pragma unroll
  for (int j=0;j<4;++j)
    #pragma unroll
    for (int rr=0;rr<4;++rr){
      int i  = wv*16 + quad*4 + rr;
      int cj = j*16 + l16;
      sK[i*72 + cj] = f2b((i >= cj) ? accS[j][rr] : 0.f);
    }

  // att = Q @ KV_prefix (state converted bf16 on the fly)
  f32x4 accO[4];
  #pragma unroll
  for (int j=0;j<4;++j) accO[j] = (f32x4){0.f,0.f,0.f,0.f};
  #pragma unroll
  for (int kk=0;kk<2;++kk){
    short8 a = *(const short8*)&sQ[(wv*16 + l16)*72 + kk*32 + quad*8];
    #pragma unroll
    for (int j=0;j<4;++j){
      const float* pf = &sKV[(j*16 + l16)*68 + kk*32 + quad*8];
      short8 bb;
      #pragma unroll
      for (int e=0;e<8;++e) ((unsigned short*)&bb)[e] = f2b(pf[e]);
      accO[j] = __builtin_amdgcn_mfma_f32_16x16x32_bf16(a, bb, accO[j], 0,0,0);
    }
  }
  __syncthreads();   // S visible to all waves

  // att += S @ V
  #pragma unroll
  for (int kk=0;kk<2;++kk){
    short8 a = *(const short8*)&sK[(wv*16 + l16)*72 + kk*32 + quad*8];
    #pragma unroll
    for (int j=0;j<4;++j){
      short8 bb = *(const short8*)&sVt[(j*16 + l16)*72 + kk*32 + quad*8];
      accO[j] = __builtin_amdgcn_mfma_f32_16x16x32_bf16(a, bb, accO[j], 0,0,0);
    }
  }
  #pragma unroll
  for (int j=0;j<4;++j)
    #pragma unroll
    for (int rr=0;rr<4;++rr){
      int i  = wv*16 + quad*4 + rr;
      int cj = j*16 + l16;
      att[base + (size_t)i*ATT_D + cj] = f2b(accO[j][rr]);
    }
}

// ---------- residual add (+ fp32 partials + bias) + LN (optional 2nd LN) ----
// xalt (nullable): read residual base from raw input (fp32/bf16 per isbf)
// instead of x_f -- used by layer-0 ln1 so ingest needn't copy x_f.
__global__ __launch_bounds__(256) void add_ln_kernel(
    const float* x, const void* xalt, const float* p, int np, const float* bias,
    const float* g, const float* bta, const float* g2, const float* b2,
    float* outf, unsigned short* outb, void* outd, const void* dsrc, int rows)
{
  int isbf = 0;
  if (dsrc) isbf = detect_isbf_block(dsrc);
  int row = blockIdx.x*4 + (threadIdx.x >> 6);
  int lane = threadIdx.x & 63;
  if (row >= rows) return;
  float a[8];
  if (xalt){
    if (isbf){
      const unsigned short* xr = (const unsigned short*)xalt + (size_t)row*512;
      short8 u0 = *(const short8*)(xr + lane*4*2);        // 8 bf16 (elems 0..7 of lane's pair)
      // layout: each lane handles elems [lane*4, lane*4+3] and [256+lane*4, ...]
      // read as two 8B chunks to match fp32 path exactly:
      const unsigned short* p0 = xr + lane*4;
      const unsigned short* p1 = xr + 256 + lane*4;
      (void)u0;
      #pragma unroll
      for (int e=0;e<4;++e){ a[e] = b2f(p0[e]); a[4+e] = b2f(p1[e]); }
    } else {
      const float* xr = (const float*)xalt + (size_t)row*512;
      *(float4*)&a[0] = *(const float4*)(xr + lane*4);
      *(float4*)&a[4] = *(const float4*)(xr + 256 + lane*4);
    }
  } else {
    const float* xr = x + (size_t)row*512;
    *(float4*)&a[0] = *(const float4*)(xr + lane*4);
    *(float4*)&a[4] = *(const float4*)(xr + 256 + lane*4);
  }
  for (int s = 0; s < np; ++s){
    const float* pr = p + (size_t)s*1048576 + (size_t)row*512;
    float yb[8];
    *(float4*)&yb[0] = *(const float4*)(pr + lane*4);
    *(float4*)&yb[4] = *(const float4*)(pr + 256 + lane*4);
    #pragma unroll
    for (int e=0;e<8;++e) a[e] += yb[e];
  }
  if (bias){
    float bb2[8];
    *(float4*)&bb2[0] = *(const float4*)(bias + lane*4);
    *(float4*)&bb2[4] = *(const float4*)(bias + 256 + lane*4);
    #pragma unroll
    for (int e=0;e<8;++e) a[e] += bb2[e];
  }
  float s = 0.f, qq = 0.f;
  #pragma unroll
  for (int e=0;e<8;++e){ s += a[e]; qq += a[e]*a[e]; }
  #pragma unroll
  for (int off=32; off>0; off>>=1){
    s  += __shfl_xor(s,  off, 64);
    qq += __shfl_xor(qq, off, 64);
  }
  float mean = s * (1.f/512.f);
  float var  = qq * (1.f/512.f) - mean*mean;
  float rstd = rsqrtf(var + 1e-5f);
  float gg[8], bb[8];
  *(float4*)&gg[0] = *(const float4*)(g + lane*4);
  *(float4*)&gg[4] = *(const float4*)(g + 256 + lane*4);
  *(float4*)&bb[0] = *(const float4*)(bta + lane*4);
  *(float4*)&bb[4] = *(const float4*)(bta + 256 + lane*4);
  #pragma unroll
  for (int e=0;e<8;++e) a[e] = (a[e]-mean)*rstd*gg[e] + bb[e];
  if (g2){   // fused final encoder LN (verified R5/R7/R8)
    float s2 = 0.f, q2 = 0.f;
    #pragma unroll
    for (int e=0;e<8;++e){ s2 += a[e]; q2 += a[e]*a[e]; }
    #pragma unroll
    for (int off=32; off>0; off>>=1){
      s2 += __shfl_xor(s2, off, 64);
      q2 += __shfl_xor(q2, off, 64);
    }
    float m2 = s2 * (1.f/512.f);
    float v2 = q2 * (1.f/512.f) - m2*m2;
    float r2 = rsqrtf(v2 + 1e-5f);
    float gg2[8], bb22[8];
    *(float4*)&gg2[0]  = *(const float4*)(g2 + lane*4);
    *(float4*)&gg2[4]  = *(const float4*)(g2 + 256 + lane*4);
    *(float4*)&bb22[0] = *(const float4*)(b2 + lane*4);
    *(float4*)&bb22[4] = *(const float4*)(b2 + 256 + lane*4);
    #pragma unroll
    for (int e=0;e<8;++e) a[e] = (a[e]-m2)*r2*gg2[e] + bb22[e];
  }
  if (outf){
    float* orow = outf + (size_t)row*512;
    *(float4*)(orow + lane*4)       = *(float4*)&a[0];
    *(float4*)(orow + 256 + lane*4) = *(float4*)&a[4];
  }
  if (outb){
    unsigned short* orow = outb + (size_t)row*512;
    #pragma unroll
    for (int e=0;e<4;++e){ orow[lane*4+e] = f2b(a[e]); orow[256+lane*4+e] = f2b(a[4+e]); }
  }
  if (outd){
    if (isbf){
      unsigned short* od = (unsigned short*)outd + (size_t)row*512;
      #pragma unroll
      for (int e=0;e<4;++e){ od[lane*4+e] = f2b(a[e]); od[256+lane*4+e] = f2b(a[4+e]); }
    } else {
      float* od = (float*)outd + (size_t)row*512;
      *(float4*)(od + lane*4)       = *(float4*)&a[0];
      *(float4*)(od + 256 + lane*4) = *(float4*)&a[4];
    }
  }
}

// ---------- host ----------
extern "C" void kernel_launch(void* const* d_in, const int* in_sizes, int n_in,
                              void* d_out, int out_size, void* d_ws, size_t ws_size,
                              hipStream_t stream)
{
  (void)in_sizes; (void)n_in; (void)out_size; (void)ws_size;
  const void* src = d_in[0];
  const void* Wq = d_in[1];  const void* bq = d_in[2];
  const void* Wk = d_in[3];  const void* bk = d_in[4];
  const void* Wv = d_in[5];  const void* bv = d_in[6];
  const void* Wo = d_in[7];  const void* bo = d_in[8];
  const void* W1 = d_in[9];  const void* b1 = d_in[10];
  const void* W2 = d_in[11]; const void* b2 = d_in[12];
  const void* g1 = d_in[13]; const void* be1 = d_in[14];
  const void* g2 = d_in[15]; const void* be2 = d_in[16];
  const void* gf = d_in[17]; const void* bef = d_in[18];

  char* W = (char*)d_ws;
  float* smalls          = (float*)(W + 256);        // 14336 floats (permuted layout)
  unsigned short* wt     = (unsigned short*)(W + 65536);
  float* x_f             = (float*)(W + 12648448);
  unsigned short* x_b    = (unsigned short*)(W + 16842752);
  unsigned short* q_b    = (unsigned short*)(W + 18939904);  // q,k,v contiguous (2MB each)
  unsigned short* att_b  = (unsigned short*)(W + 25231360);
  float* pp              = (float*)(W + 27328512);   // 4 partial buffers, 4MB fp32 each
  unsigned short* h1_b   = (unsigned short*)(W + 44105728);  // 8MB
  float* states          = (float*)(W + 44105728);   // aliases h1_b (disjoint lifetime)
  unsigned short* k_b = q_b + 1048576;
  unsigned short* v_b = q_b + 2097152;

  // ---- combined ingest (x_f copy dropped)
  IngestParams ip;
  {
    const void* wsrc[6] = {Wq, Wk, Wv, Wo, W1, W2};
    int wK[6] = {512,512,512,512,512,2048};
    int wN[6] = {512,512,512,512,2048,512};
    long wsz[6] = {262144,262144,262144,262144,1048576,1048576};
    int tstart = 0; size_t dsto = 0;
    for (int l=0;l<2;++l)
      for (int ti=0;ti<6;++ti){
        int idx = l*6+ti;
        ip.w[idx].src = wsrc[ti];
        ip.w[idx].src_off = (long)l * wsz[ti];
        ip.w[idx].dst = wt + dsto;
        ip.w[idx].K = wK[ti]; ip.w[idx].N = wN[ti];
        ip.w[idx].tstart = tstart;
        tstart += (wK[ti]/32)*(wN[ti]/32);
        dsto += (size_t)wsz[ti];
      }
    const void* ss[10] = {bq,bk,bv,bo,b1,b2,g1,be1,g2,be2};
    int slen[10] = {512,512,512,512,2048,512,512,512,512,512};
    int dcur = 0, di = 0;
    for (int l=0;l<2;++l)
      for (int ti=0;ti<10;++ti){
        ip.s[di].src = ss[ti];
        ip.s[di].src_off = l * slen[ti];
        ip.s[di].dstart = dcur;
        dcur += slen[ti]; ++di;
      }
    ip.s[20].src = gf;  ip.s[20].src_off = 0; ip.s[20].dstart = dcur; dcur += 512;
    ip.s[21].src = bef; ip.s[21].src_off = 0; ip.s[21].dstart = dcur; dcur += 512;
    ip.sdst = smalls; ip.stotal = dcur;   // 14336
    ip.src = src; ip.xb = x_b;
    ingest_all<<<dim3(10296), 256, 0, stream>>>(ip);
  }

  for (int l = 0; l < 2; ++l){
    unsigned short* WqkvT = wt + (size_t)l*3145728;   // [1536][512]
    unsigned short* WoT   = WqkvT + 786432;           // [512][512]
    unsigned short* W1T   = WqkvT + 1048576;          // [2048][512]
    unsigned short* W2T   = WqkvT + 2097152;          // [512][2048]
    float* base  = smalls + l*6656;
    float* p_bqkv= base;           // 1536
    float* p_bo  = base + 1536;
    float* p_b1  = base + 2048;    // 2048
    float* p_b2  = base + 4096;
    float* p_g1  = base + 4608;
    float* p_be1 = base + 5120;
    float* p_g2  = base + 5632;
    float* p_be2 = base + 6144;

    // QKV: one GEMM, N=1536, BN=64 (R4-proven)
    GemmArgs qkv = {};
    qkv.A = x_b; qkv.Bt = WqkvT; qkv.bias = p_bqkv;
    qkv.Cf = nullptr; qkv.Cb = q_b;
    qkv.K = 512; qkv.lda = 512; qkv.ldb = 512; qkv.ldc = 512;
    qkv.cshift = 9; qkv.cmask = 511; qkv.cstride = 1048576; qkv.cfz = 0; qkv.relu = 0;
    gemm_bt<64><<<dim3(24,16,1), 256, 0, stream>>>(qkv);

    attn_state_kernel<<<dim3(16,16), 256, 0, stream>>>(k_b, v_b, states);
    attn_out_kernel<<<dim3(16,16), 256, 0, stream>>>(q_b, k_b, v_b, states, att_b);

    // att @ Wo: K-split 2 -> fp32 partials (bias folded into LN)
    GemmArgs go = {};
    go.A = att_b; go.Bt = WoT; go.bias = nullptr;
    go.Cf = pp; go.Cb = nullptr;
    go.K = 256; go.lda = 512; go.ldb = 512; go.ldc = 512;
    go.cshift = 30; go.cmask = 0x3fffffff; go.cstride = 0; go.cfz = 1048576; go.relu = 0;
    gemm_bt<64><<<dim3(8,16,2), 256, 0, stream>>>(go);

    // ln1: layer 0 reads residual from src directly (xalt), later from x_f
    if (l == 0)
      add_ln_kernel<<<dim3(512), 256, 0, stream>>>(nullptr, src, pp, 2, p_bo,
                                                   p_g1, p_be1, nullptr, nullptr,
                                                   x_f, x_b, nullptr, src, 2048);
    else
      add_ln_kernel<<<dim3(512), 256, 0, stream>>>(x_f, nullptr, pp, 2, p_bo,
                                                   p_g1, p_be1, nullptr, nullptr,
                                                   x_f, x_b, nullptr, nullptr, 2048);

    // FFN up: BN=64, grid (32,16) = 512 blocks = 2 blocks/CU (R8-proven)
    GemmArgs f1 = {};
    f1.A = x_b; f1.Bt = W1T; f1.bias = p_b1;
    f1.Cf = nullptr; f1.Cb = h1_b;
    f1.K = 512; f1.lda = 512; f1.ldb = 512; f1.ldc = 2048;
    f1.cshift = 30; f1.cmask = 0x3fffffff; f1.cstride = 0; f1.cfz = 0; f1.relu = 1;
    gemm_bt<64><<<dim3(32,16,1), 256, 0, stream>>>(f1);

    // FFN down: K-split 4 (512 blocks = 2/CU, K=512 = 8 K-tiles -- the f1
    // shape that won in R8; was split-2 at 1/CU)
    GemmArgs f2 = {};
    f2.A = h1_b; f2.Bt = W2T; f2.bias = nullptr;
    f2.Cf = pp; f2.Cb = nullptr;
    f2.K = 512; f2.lda = 2048; f2.ldb = 2048; f2.ldc = 512;
    f2.cshift = 30; f2.cmask = 0x3fffffff; f2.cstride = 0; f2.cfz = 1048576; f2.relu = 0;
    gemm_bt<64><<<dim3(8,16,4), 256, 0, stream>>>(f2);

    if (l == 0){
      add_ln_kernel<<<dim3(512), 256, 0, stream>>>(x_f, nullptr, pp, 4, p_b2,
                                                   p_g2, p_be2, nullptr, nullptr,
                                                   x_f, x_b, nullptr, nullptr, 2048);
    } else {
      // ln2 fused with final encoder LN -> d_out (dtype follows input)
      add_ln_kernel<<<dim3(512), 256, 0, stream>>>(x_f, nullptr, pp, 4, p_b2,
                                                   p_g2, p_be2,
                                                   smalls + 13312, smalls + 13824,
                                                   nullptr, nullptr, d_out, src, 2048);
    }
  }
}

// Round 10
// 244.863 us; speedup vs baseline: 3.7876x; 1.0349x over previous
//
#include <hip/hip_runtime.h>
#include <hip/hip_bf16.h>

#define DEV static __device__ __forceinline__

typedef __attribute__((ext_vector_type(8))) short short8;
typedef __attribute__((ext_vector_type(4))) float f32x4;

// ---------- helpers ----------
DEV unsigned short f2b(float f){
  unsigned int u = __float_as_uint(f);
  return (unsigned short)((u + 0x7FFFu + ((u >> 16) & 1u)) >> 16);  // RNE
}
DEV float b2f(unsigned short h){ return __uint_as_float(((unsigned int)h) << 16); }
DEV float load_in(const void* p, size_t i, int isbf){
  return isbf ? b2f(((const unsigned short*)p)[i]) : ((const float*)p)[i];
}
DEV void load_lds16(const unsigned short* g, unsigned short* l){
  __builtin_amdgcn_global_load_lds(
      (const __attribute__((address_space(1))) void*)g,
      (__attribute__((address_space(3))) void*)l, 16, 0, 0);
}

// ---------- per-block dtype detection ----------
DEV int detect_isbf_block(const void* src){
  __shared__ int cnt[4];
  int tid = threadIdx.x;
  float v = b2f(((const unsigned short*)src)[2 * tid]);
  float av = fabsf(v);
  bool sane = ((av < 64.0f) && (av > 9.5e-7f)) || (v == 0.0f);
  unsigned long long m = __ballot(sane);
  if ((tid & 63) == 0) cnt[tid >> 6] = __popcll(m);
  __syncthreads();
  int tot = cnt[0] + cnt[1] + cnt[2] + cnt[3];
  __syncthreads();
  return tot > 128;
}

// ---------- combined ingest: weights transpose + src bf16 + smalls ----------
struct WDesc { const void* src; long src_off; unsigned short* dst; int K; int N; int tstart; };
struct SDesc { const void* src; int src_off; int dstart; };
struct IngestParams {
  WDesc w[12];
  SDesc s[22];
  float* sdst; int stotal;
  const void* src;
  unsigned short* xb;
};

__global__ __launch_bounds__(256) void ingest_all(IngestParams P){
  __shared__ float tile[32][33];
  int b = blockIdx.x, tid = threadIdx.x;
  int isbf = detect_isbf_block(P.src);
  if (b < 6144){
    int t = 0;
    #pragma unroll
    for (int i = 1; i < 12; ++i) if (b >= P.w[i].tstart) t = i;
    WDesc d = P.w[t];
    int r = b - d.tstart;
    int tiles_x = d.N >> 5;
    int tx = r % tiles_x, ty = r / tiles_x;
    int lx = tid & 31, ly = tid >> 5;   // 32 x 8
    #pragma unroll
    for (int i = 0; i < 4; ++i){
      int row = ty*32 + ly + i*8;
      int col = tx*32 + lx;
      tile[ly + i*8][lx] = load_in(d.src, (size_t)d.src_off + (size_t)row*d.N + col, isbf);
    }
    __syncthreads();
    #pragma unroll
    for (int i = 0; i < 4; ++i){
      int orow = tx*32 + ly + i*8;   // n
      int ocol = ty*32 + lx;         // k
      d.dst[(size_t)orow*d.K + ocol] = f2b(tile[lx][ly + i*8]);
    }
    return;
  }
  int mb = b - 6144;
  if (mb < 4096){
    int i = mb*256 + tid;
    P.xb[i] = f2b(load_in(P.src, (size_t)i, isbf));
  } else {
    int i = (mb - 4096)*256 + tid;
    if (i < P.stotal){
      int t = 0;
      #pragma unroll
      for (int j = 1; j < 22; ++j) if (i >= P.s[j].dstart) t = j;
      P.sdst[i] = load_in(P.s[t].src, (size_t)P.s[t].src_off + (i - P.s[t].dstart), isbf);
    }
  }
}

// ---------- GEMM: C[M][N] = A[M][K] @ Bt[N][K]^T (+bias) (A,Bt bf16) ----------
// BN fixed 64; BM templated (64 or 128). BM=64 -> 32KB LDS/block -> up to
// 4 blocks/CU co-resident: co-resident blocks' waves compute through each
// other's vmcnt-drain barrier stalls (m114 overlap; R8/R9-proven at 2/CU).
// MFMA sequence per output element is identical for any BM -> bit-identical C.
struct GemmArgs {
  const unsigned short* A;
  const unsigned short* Bt;
  const float* bias;      // nullable
  float* Cf;              // nullable (fp32 partial base)
  unsigned short* Cb;     // nullable (bf16 out)
  int K;                  // per-split K
  int lda, ldb, ldc;
  int cshift, cmask;
  size_t cstride;         // col-split stride (elements)
  size_t cfz;             // Cf z-stride (elements)
  int relu;
};

template<int BM>
__global__ __launch_bounds__(256) void gemm_bt(GemmArgs g){
  constexpr int NI = BM / 64;             // 16-row fragments per wave
  constexpr int NJ = 4;
  constexpr int APASS = BM / 32;          // 32-row staging passes for A
  constexpr int WROWS = BM / 4;           // rows per wave
  __shared__ __align__(16) unsigned short sA[2][BM*64];
  __shared__ __align__(16) unsigned short sB[2][64*64];
  int tid = threadIdx.x;
  int koff = blockIdx.z * g.K;
  int K = g.K, lda = g.lda, ldb = g.ldb;
  size_t bm = (size_t)blockIdx.y * BM, bn = (size_t)blockIdx.x * 64;
  int lane = tid & 63, wv = tid >> 6, quad = lane >> 4, l16 = lane & 15;
  int wm = wv * WROWS;
  f32x4 acc[NI][NJ];
  #pragma unroll
  for (int i=0;i<NI;++i)
    #pragma unroll
    for (int j=0;j<NJ;++j) acc[i][j] = (f32x4){0.f,0.f,0.f,0.f};
  int srow = tid >> 3;                    // 0..31 within pass
  int schunk = (tid & 7) ^ (srow & 7);
  const unsigned short* Ap = g.A  + (bm + srow)*lda + koff + schunk*8;
  const unsigned short* Bp = g.Bt + (bn + srow)*ldb + koff + schunk*8;

  #define STAGE(buf, ko)                                                      \
    do {                                                                      \
      _Pragma("unroll")                                                       \
      for (int p = 0; p < APASS; ++p)                                         \
        load_lds16(Ap + (size_t)(p*32)*lda + (ko), &sA[buf][p*2048 + tid*8]); \
      _Pragma("unroll")                                                       \
      for (int p = 0; p < 2; ++p)                                             \
        load_lds16(Bp + (size_t)(p*32)*ldb + (ko), &sB[buf][p*2048 + tid*8]); \
    } while (0)

  STAGE(0, 0);
  asm volatile("s_waitcnt vmcnt(0)" ::: "memory");
  __builtin_amdgcn_s_barrier();

  int nt = K >> 6;
  int cur = 0;
  for (int t = 0; t < nt; ++t){
    if (t + 1 < nt){
      STAGE(cur ^ 1, (t + 1) * 64);       // issue next-tile loads early
      __builtin_amdgcn_sched_barrier(0);  // keep issue before compute
    }
    #pragma unroll
    for (int kk = 0; kk < 2; ++kk){
      short8 af[NI], bfv[NJ];
      #pragma unroll
      for (int i=0;i<NI;++i){
        int row = wm + i*16 + l16;
        int ch  = (kk*4 + quad) ^ (row & 7);
        af[i] = *(const short8*)&sA[cur][row*64 + ch*8];
      }
      #pragma unroll
      for (int j=0;j<NJ;++j){
        int row = j*16 + l16;
        int ch  = (kk*4 + quad) ^ (row & 7);
        bfv[j] = *(const short8*)&sB[cur][row*64 + ch*8];
      }
      #pragma unroll
      for (int i=0;i<NI;++i)
        #pragma unroll
        for (int j=0;j<NJ;++j)
          acc[i][j] = __builtin_amdgcn_mfma_f32_16x16x32_bf16(af[i], bfv[j], acc[i][j], 0,0,0);
    }
    if (t + 1 < nt){
      asm volatile("s_waitcnt vmcnt(0)" ::: "memory");
      __builtin_amdgcn_s_barrier();
    }
    cur ^= 1;
  }
  #undef STAGE

  float* Cf = g.Cf ? g.Cf + (size_t)blockIdx.z * g.cfz : nullptr;
  unsigned short* Cb = g.Cb;
  #pragma unroll
  for (int j=0;j<NJ;++j){
    int col = (int)bn + j*16 + l16;
    float bv = g.bias ? g.bias[col] : 0.f;
    size_t cbase = ((size_t)(col >> g.cshift))*g.cstride + (col & g.cmask);
    #pragma unroll
    for (int i=0;i<NI;++i){
      #pragma unroll
      for (int r=0;r<4;++r){
        int row = (int)bm + wm + i*16 + quad*4 + r;
        float v = acc[i][j][r] + bv;
        if (g.relu) v = fmaxf(v, 0.f);
        size_t idx = cbase + (size_t)row*g.ldc;
        if (Cf) Cf[idx] = v;
        if (Cb) Cb[idx] = f2b(v);
      }
    }
  }
}

// ---------- chunked causal linear attention, parallel over (bh, chunk) ----------
#define ATT_S 1024
#define ATT_D 512

// Pass A: states[bh][c] = V_c^T K_c   (64x64 fp32)
__global__ __launch_bounds__(256) void attn_state_kernel(
    const unsigned short* k, const unsigned short* v, float* states)
{
  __shared__ __align__(16) unsigned short sVt[64*72];
  __shared__ __align__(16) unsigned short sKt[64*72];
  int tid = threadIdx.x;
  int c = blockIdx.x, bh = blockIdx.y;
  int b = bh >> 3, h = bh & 7;
  const size_t base = ((size_t)b*ATT_S + (size_t)c*64)*ATT_D + h*64;
  int lane = tid & 63, wv = tid >> 6, quad = lane >> 4, l16 = lane & 15;

  int t = lane, vc = wv*8;
  const unsigned short* vp = v + base + (size_t)t*ATT_D;
  const unsigned short* kp = k + base + (size_t)t*ATT_D;
  float4 v0 = *(const float4*)(vp + vc);
  float4 v1 = *(const float4*)(vp + vc + 32);
  float4 k0 = *(const float4*)(kp + vc);
  float4 k1 = *(const float4*)(kp + vc + 32);
  {
    const unsigned short* pv0 = (const unsigned short*)&v0;
    const unsigned short* pv1 = (const unsigned short*)&v1;
    const unsigned short* pk0 = (const unsigned short*)&k0;
    const unsigned short* pk1 = (const unsigned short*)&k1;
    #pragma unroll
    for (int e = 0; e < 8; ++e){
      sVt[(vc+e)*72 + t]    = pv0[e];
      sVt[(vc+32+e)*72 + t] = pv1[e];
      sKt[(vc+e)*72 + t]    = pk0[e];
      sKt[(vc+32+e)*72 + t] = pk1[e];
    }
  }
  __syncthreads();

  f32x4 acc[4];
  #pragma unroll
  for (int j=0;j<4;++j) acc[j] = (f32x4){0.f,0.f,0.f,0.f};
  #pragma unroll
  for (int kk=0;kk<2;++kk){
    short8 a = *(const short8*)&sVt[(wv*16 + l16)*72 + kk*32 + quad*8];
    #pragma unroll
    for (int j=0;j<4;++j){
      short8 bb = *(const short8*)&sKt[(j*16 + l16)*72 + kk*32 + quad*8];
      acc[j] = __builtin_amdgcn_mfma_f32_16x16x32_bf16(a, bb, acc[j], 0,0,0);
    }
  }
  float* st = states + ((size_t)bh*16 + c)*4096;
  #pragma unroll
  for (int j=0;j<4;++j)
    #pragma unroll
    for (int rr=0;rr<4;++rr)
      st[(wv*16 + quad*4 + rr)*64 + j*16 + l16] = acc[j][rr];
}

// Pass B: att_c = Q_c @ (sum_{cc<c} states[cc]) + tril(Q_c K_c^T) @ V_c
__global__ __launch_bounds__(256) void attn_out_kernel(
    const unsigned short* q, const unsigned short* k, const unsigned short* v,
    const float* states, unsigned short* att)
{
  __shared__ __align__(16) unsigned short sQ [64*72];
  __shared__ __align__(16) unsigned short sK [64*72];   // K chunk, reused for S
  __shared__ __align__(16) unsigned short sVt[64*72];
  __shared__ __align__(16) float sKV[64*68];
  int tid = threadIdx.x;
  int c = blockIdx.x, bh = blockIdx.y;
  int b = bh >> 3, h = bh & 7;
  const size_t base = ((size_t)b*ATT_S + (size_t)c*64)*ATT_D + h*64;
  int lane = tid & 63, wv = tid >> 6, quad = lane >> 4, l16 = lane & 15;

  // exclusive prefix sum of chunk states (fp32)
  float4 racc[4];
  #pragma unroll
  for (int u=0;u<4;++u) racc[u] = (float4){0.f,0.f,0.f,0.f};
  const float* sbase = states + (size_t)bh*16*4096;
  for (int cc = 0; cc < c; ++cc){
    const float4* sp = (const float4*)(sbase + (size_t)cc*4096);
    #pragma unroll
    for (int u=0;u<4;++u){
      float4 t4 = sp[tid + u*256];
      racc[u].x += t4.x; racc[u].y += t4.y; racc[u].z += t4.z; racc[u].w += t4.w;
    }
  }
  #pragma unroll
  for (int u=0;u<4;++u){
    int e = (tid + u*256)*4;
    int row = e >> 6, col = e & 63;
    *(float4*)&sKV[row*68 + col] = racc[u];
  }

  // stage Q, K row-major; V transposed
  int r = tid >> 2, c8 = (tid & 3)*8;
  const unsigned short* qp = q + base + (size_t)r*ATT_D;
  const unsigned short* kp = k + base + (size_t)r*ATT_D;
  float4 q0 = *(const float4*)(qp + c8);
  float4 q1 = *(const float4*)(qp + c8 + 32);
  float4 k0 = *(const float4*)(kp + c8);
  float4 k1 = *(const float4*)(kp + c8 + 32);
  int t = lane, vc = wv*8;
  const unsigned short* vp = v + base + (size_t)t*ATT_D;
  float4 v0 = *(const float4*)(vp + vc);
  float4 v1 = *(const float4*)(vp + vc + 32);
  *(float4*)&sQ[r*72 + c8]      = q0;
  *(float4*)&sQ[r*72 + c8 + 32] = q1;
  *(float4*)&sK[r*72 + c8]      = k0;
  *(float4*)&sK[r*72 + c8 + 32] = k1;
  {
    const unsigned short* pv0 = (const unsigned short*)&v0;
    const unsigned short* pv1 = (const unsigned short*)&v1;
    #pragma unroll
    for (int e=0;e<8;++e){
      sVt[(vc+e)*72 + t]    = pv0[e];
      sVt[(vc+32+e)*72 + t] = pv1[e];
    }
  }
  __syncthreads();

  // S = Q K^T
  f32x4 accS[4];
  #pragma unroll
  for (int j=0;j<4;++j) accS[j] = (f32x4){0.f,0.f,0.f,0.f};
  #pragma unroll
  for (int kk=0;kk<2;++kk){
    short8 a = *(const short8*)&sQ[(wv*16 + l16)*72 + kk*32 + quad*8];
    #pragma unroll
    for (int j=0;j<4;++j){
      short8 bb = *(const short8*)&sK[(j*16 + l16)*72 + kk*32 + quad*8];
      accS[j] = __builtin_amdgcn_mfma_f32_16x16x32_bf16(a, bb, accS[j], 0,0,0);
    }
  }
  __syncthreads();   // all waves done reading sK

  // masked S -> sK (bf16)
  #pragma unroll
  for (int j=0;j<4;++j)
    #pragma unroll
    for (int rr=0;rr<4;++rr){
      int i  = wv*16 + quad*4 + rr;
      int cj = j*16 + l16;
      sK[i*72 + cj] = f2b((i >= cj) ? accS[j][rr] : 0.f);
    }

  // att = Q @ KV_prefix (state converted bf16 on the fly)
  f32x4 accO[4];
  #pragma unroll
  for (int j=0;j<4;++j) accO[j] = (f32x4){0.f,0.f,0.f,0.f};
  #pragma unroll
  for (int kk=0;kk<2;++kk){
    short8 a = *(const short8*)&sQ[(wv*16 + l16)*72 + kk*32 + quad*8];
    #pragma unroll
    for (int j=0;j<4;++j){
      const float* pf = &sKV[(j*16 + l16)*68 + kk*32 + quad*8];
      short8 bb;
      #pragma unroll
      for (int e=0;e<8;++e) ((unsigned short*)&bb)[e] = f2b(pf[e]);
      accO[j] = __builtin_amdgcn_mfma_f32_16x16x32_bf16(a, bb, accO[j], 0,0,0);
    }
  }
  __syncthreads();   // S visible to all waves

  // att += S @ V
  #pragma unroll
  for (int kk=0;kk<2;++kk){
    short8 a = *(const short8*)&sK[(wv*16 + l16)*72 + kk*32 + quad*8];
    #pragma unroll
    for (int j=0;j<4;++j){
      short8 bb = *(const short8*)&sVt[(j*16 + l16)*72 + kk*32 + quad*8];
      accO[j] = __builtin_amdgcn_mfma_f32_16x16x32_bf16(a, bb, accO[j], 0,0,0);
    }
  }
  #pragma unroll
  for (int j=0;j<4;++j)
    #pragma unroll
    for (int rr=0;rr<4;++rr){
      int i  = wv*16 + quad*4 + rr;
      int cj = j*16 + l16;
      att[base + (size_t)i*ATT_D + cj] = f2b(accO[j][rr]);
    }
}

// ---------- residual add (+ fp32 partials + bias) + LN (optional 2nd LN) ----
// xalt (nullable): read residual base from raw input (fp32/bf16 per isbf).
__global__ __launch_bounds__(256) void add_ln_kernel(
    const float* x, const void* xalt, const float* p, int np, const float* bias,
    const float* g, const float* bta, const float* g2, const float* b2,
    float* outf, unsigned short* outb, void* outd, const void* dsrc, int rows)
{
  int isbf = 0;
  if (dsrc) isbf = detect_isbf_block(dsrc);
  int row = blockIdx.x*4 + (threadIdx.x >> 6);
  int lane = threadIdx.x & 63;
  if (row >= rows) return;
  float a[8];
  if (xalt){
    if (isbf){
      const unsigned short* xr = (const unsigned short*)xalt + (size_t)row*512;
      const unsigned short* p0 = xr + lane*4;
      const unsigned short* p1 = xr + 256 + lane*4;
      #pragma unroll
      for (int e=0;e<4;++e){ a[e] = b2f(p0[e]); a[4+e] = b2f(p1[e]); }
    } else {
      const float* xr = (const float*)xalt + (size_t)row*512;
      *(float4*)&a[0] = *(const float4*)(xr + lane*4);
      *(float4*)&a[4] = *(const float4*)(xr + 256 + lane*4);
    }
  } else {
    const float* xr = x + (size_t)row*512;
    *(float4*)&a[0] = *(const float4*)(xr + lane*4);
    *(float4*)&a[4] = *(const float4*)(xr + 256 + lane*4);
  }
  for (int s = 0; s < np; ++s){
    const float* pr = p + (size_t)s*1048576 + (size_t)row*512;
    float yb[8];
    *(float4*)&yb[0] = *(const float4*)(pr + lane*4);
    *(float4*)&yb[4] = *(const float4*)(pr + 256 + lane*4);
    #pragma unroll
    for (int e=0;e<8;++e) a[e] += yb[e];
  }
  if (bias){
    float bb2[8];
    *(float4*)&bb2[0] = *(const float4*)(bias + lane*4);
    *(float4*)&bb2[4] = *(const float4*)(bias + 256 + lane*4);
    #pragma unroll
    for (int e=0;e<8;++e) a[e] += bb2[e];
  }
  float s = 0.f, qq = 0.f;
  #pragma unroll
  for (int e=0;e<8;++e){ s += a[e]; qq += a[e]*a[e]; }
  #pragma unroll
  for (int off=32; off>0; off>>=1){
    s  += __shfl_xor(s,  off, 64);
    qq += __shfl_xor(qq, off, 64);
  }
  float mean = s * (1.f/512.f);
  float var  = qq * (1.f/512.f) - mean*mean;
  float rstd = rsqrtf(var + 1e-5f);
  float gg[8], bb[8];
  *(float4*)&gg[0] = *(const float4*)(g + lane*4);
  *(float4*)&gg[4] = *(const float4*)(g + 256 + lane*4);
  *(float4*)&bb[0] = *(const float4*)(bta + lane*4);
  *(float4*)&bb[4] = *(const float4*)(bta + 256 + lane*4);
  #pragma unroll
  for (int e=0;e<8;++e) a[e] = (a[e]-mean)*rstd*gg[e] + bb[e];
  if (g2){   // fused final encoder LN (verified R5/R7/R8/R9)
    float s2 = 0.f, q2 = 0.f;
    #pragma unroll
    for (int e=0;e<8;++e){ s2 += a[e]; q2 += a[e]*a[e]; }
    #pragma unroll
    for (int off=32; off>0; off>>=1){
      s2 += __shfl_xor(s2, off, 64);
      q2 += __shfl_xor(q2, off, 64);
    }
    float m2 = s2 * (1.f/512.f);
    float v2 = q2 * (1.f/512.f) - m2*m2;
    float r2 = rsqrtf(v2 + 1e-5f);
    float gg2[8], bb22[8];
    *(float4*)&gg2[0]  = *(const float4*)(g2 + lane*4);
    *(float4*)&gg2[4]  = *(const float4*)(g2 + 256 + lane*4);
    *(float4*)&bb22[0] = *(const float4*)(b2 + lane*4);
    *(float4*)&bb22[4] = *(const float4*)(b2 + 256 + lane*4);
    #pragma unroll
    for (int e=0;e<8;++e) a[e] = (a[e]-m2)*r2*gg2[e] + bb22[e];
  }
  if (outf){
    float* orow = outf + (size_t)row*512;
    *(float4*)(orow + lane*4)       = *(float4*)&a[0];
    *(float4*)(orow + 256 + lane*4) = *(float4*)&a[4];
  }
  if (outb){
    unsigned short* orow = outb + (size_t)row*512;
    #pragma unroll
    for (int e=0;e<4;++e){ orow[lane*4+e] = f2b(a[e]); orow[256+lane*4+e] = f2b(a[4+e]); }
  }
  if (outd){
    if (isbf){
      unsigned short* od = (unsigned short*)outd + (size_t)row*512;
      #pragma unroll
      for (int e=0;e<4;++e){ od[lane*4+e] = f2b(a[e]); od[256+lane*4+e] = f2b(a[4+e]); }
    } else {
      float* od = (float*)outd + (size_t)row*512;
      *(float4*)(od + lane*4)       = *(float4*)&a[0];
      *(float4*)(od + 256 + lane*4) = *(float4*)&a[4];
    }
  }
}

// ---------- host ----------
extern "C" void kernel_launch(void* const* d_in, const int* in_sizes, int n_in,
                              void* d_out, int out_size, void* d_ws, size_t ws_size,
                              hipStream_t stream)
{
  (void)in_sizes; (void)n_in; (void)out_size; (void)ws_size;
  const void* src = d_in[0];
  const void* Wq = d_in[1];  const void* bq = d_in[2];
  const void* Wk = d_in[3];  const void* bk = d_in[4];
  const void* Wv = d_in[5];  const void* bv = d_in[6];
  const void* Wo = d_in[7];  const void* bo = d_in[8];
  const void* W1 = d_in[9];  const void* b1 = d_in[10];
  const void* W2 = d_in[11]; const void* b2 = d_in[12];
  const void* g1 = d_in[13]; const void* be1 = d_in[14];
  const void* g2 = d_in[15]; const void* be2 = d_in[16];
  const void* gf = d_in[17]; const void* bef = d_in[18];

  char* W = (char*)d_ws;
  float* smalls          = (float*)(W + 256);        // 14336 floats (permuted layout)
  unsigned short* wt     = (unsigned short*)(W + 65536);
  float* x_f             = (float*)(W + 12648448);
  unsigned short* x_b    = (unsigned short*)(W + 16842752);
  unsigned short* q_b    = (unsigned short*)(W + 18939904);  // q,k,v contiguous (2MB each)
  unsigned short* att_b  = (unsigned short*)(W + 25231360);
  float* pp              = (float*)(W + 27328512);   // 4 partial buffers, 4MB fp32 each
  unsigned short* h1_b   = (unsigned short*)(W + 44105728);  // 8MB
  float* states          = (float*)(W + 44105728);   // aliases h1_b (disjoint lifetime)
  unsigned short* k_b = q_b + 1048576;
  unsigned short* v_b = q_b + 2097152;

  // ---- combined ingest (no x_f copy)
  IngestParams ip;
  {
    const void* wsrc[6] = {Wq, Wk, Wv, Wo, W1, W2};
    int wK[6] = {512,512,512,512,512,2048};
    int wN[6] = {512,512,512,512,2048,512};
    long wsz[6] = {262144,262144,262144,262144,1048576,1048576};
    int tstart = 0; size_t dsto = 0;
    for (int l=0;l<2;++l)
      for (int ti=0;ti<6;++ti){
        int idx = l*6+ti;
        ip.w[idx].src = wsrc[ti];
        ip.w[idx].src_off = (long)l * wsz[ti];
        ip.w[idx].dst = wt + dsto;
        ip.w[idx].K = wK[ti]; ip.w[idx].N = wN[ti];
        ip.w[idx].tstart = tstart;
        tstart += (wK[ti]/32)*(wN[ti]/32);
        dsto += (size_t)wsz[ti];
      }
    const void* ss[10] = {bq,bk,bv,bo,b1,b2,g1,be1,g2,be2};
    int slen[10] = {512,512,512,512,2048,512,512,512,512,512};
    int dcur = 0, di = 0;
    for (int l=0;l<2;++l)
      for (int ti=0;ti<10;++ti){
        ip.s[di].src = ss[ti];
        ip.s[di].src_off = l * slen[ti];
        ip.s[di].dstart = dcur;
        dcur += slen[ti]; ++di;
      }
    ip.s[20].src = gf;  ip.s[20].src_off = 0; ip.s[20].dstart = dcur; dcur += 512;
    ip.s[21].src = bef; ip.s[21].src_off = 0; ip.s[21].dstart = dcur; dcur += 512;
    ip.sdst = smalls; ip.stotal = dcur;   // 14336
    ip.src = src; ip.xb = x_b;
    ingest_all<<<dim3(10296), 256, 0, stream>>>(ip);
  }

  for (int l = 0; l < 2; ++l){
    unsigned short* WqkvT = wt + (size_t)l*3145728;   // [1536][512]
    unsigned short* WoT   = WqkvT + 786432;           // [512][512]
    unsigned short* W1T   = WqkvT + 1048576;          // [2048][512]
    unsigned short* W2T   = WqkvT + 2097152;          // [512][2048]
    float* base  = smalls + l*6656;
    float* p_bqkv= base;           // 1536
    float* p_bo  = base + 1536;
    float* p_b1  = base + 2048;    // 2048
    float* p_b2  = base + 4096;
    float* p_g1  = base + 4608;
    float* p_be1 = base + 5120;
    float* p_g2  = base + 5632;
    float* p_be2 = base + 6144;

    // QKV: BM=64 -> grid (24,32) = 768 blocks = 3/CU uniform (was 1.5/CU)
    GemmArgs qkv = {};
    qkv.A = x_b; qkv.Bt = WqkvT; qkv.bias = p_bqkv;
    qkv.Cf = nullptr; qkv.Cb = q_b;
    qkv.K = 512; qkv.lda = 512; qkv.ldb = 512; qkv.ldc = 512;
    qkv.cshift = 9; qkv.cmask = 511; qkv.cstride = 1048576; qkv.cfz = 0; qkv.relu = 0;
    gemm_bt<64><<<dim3(24,32,1), 256, 0, stream>>>(qkv);

    attn_state_kernel<<<dim3(16,16), 256, 0, stream>>>(k_b, v_b, states);
    attn_out_kernel<<<dim3(16,16), 256, 0, stream>>>(q_b, k_b, v_b, states, att_b);

    // att @ Wo: BM=64, K-split 2 -> (8,32,2) = 512 = 2/CU (was 1/CU)
    GemmArgs go = {};
    go.A = att_b; go.Bt = WoT; go.bias = nullptr;
    go.Cf = pp; go.Cb = nullptr;
    go.K = 256; go.lda = 512; go.ldb = 512; go.ldc = 512;
    go.cshift = 30; go.cmask = 0x3fffffff; go.cstride = 0; go.cfz = 1048576; go.relu = 0;
    gemm_bt<64><<<dim3(8,32,2), 256, 0, stream>>>(go);

    // ln1: layer 0 reads residual from src directly (xalt), later from x_f
    if (l == 0)
      add_ln_kernel<<<dim3(512), 256, 0, stream>>>(nullptr, src, pp, 2, p_bo,
                                                   p_g1, p_be1, nullptr, nullptr,
                                                   x_f, x_b, nullptr, src, 2048);
    else
      add_ln_kernel<<<dim3(512), 256, 0, stream>>>(x_f, nullptr, pp, 2, p_bo,
                                                   p_g1, p_be1, nullptr, nullptr,
                                                   x_f, x_b, nullptr, nullptr, 2048);

    // FFN up: BM=64 -> (32,32) = 1024 blocks = 4/CU (was 2/CU)
    GemmArgs f1 = {};
    f1.A = x_b; f1.Bt = W1T; f1.bias = p_b1;
    f1.Cf = nullptr; f1.Cb = h1_b;
    f1.K = 512; f1.lda = 512; f1.ldb = 512; f1.ldc = 2048;
    f1.cshift = 30; f1.cmask = 0x3fffffff; f1.cstride = 0; f1.cfz = 0; f1.relu = 1;
    gemm_bt<64><<<dim3(32,32,1), 256, 0, stream>>>(f1);

    // FFN down: BM=64, K-split 4 -> (8,32,4) = 1024 = 4/CU (was 2/CU)
    GemmArgs f2 = {};
    f2.A = h1_b; f2.Bt = W2T; f2.bias = nullptr;
    f2.Cf = pp; f2.Cb = nullptr;
    f2.K = 512; f2.lda = 2048; f2.ldb = 2048; f2.ldc = 512;
    f2.cshift = 30; f2.cmask = 0x3fffffff; f2.cstride = 0; f2.cfz = 1048576; f2.relu = 0;
    gemm_bt<64><<<dim3(8,32,4), 256, 0, stream>>>(f2);

    if (l == 0){
      add_ln_kernel<<<dim3(512), 256, 0, stream>>>(x_f, nullptr, pp, 4, p_b2,
                                                   p_g2, p_be2, nullptr, nullptr,
                                                   x_f, x_b, nullptr, nullptr, 2048);
    } else {
      // ln2 fused with final encoder LN -> d_out (dtype follows input)
      add_ln_kernel<<<dim3(512), 256, 0, stream>>>(x_f, nullptr, pp, 4, p_b2,
                                                   p_g2, p_be2,
                                                   smalls + 13312, smalls + 13824,
                                                   nullptr, nullptr, d_out, src, 2048);
    }
  }
}